// Round 3
// baseline (713.746 us; speedup 1.0000x reference)
//
#include <hip/hip_runtime.h>
#include <hip/hip_bf16.h>

#define NN 50000
#define EE 800000
#define GG 16
#define QD 768
#define SCAN_BLK 49   // ceil(50000/1024)

typedef __bf16 bf16x8 __attribute__((ext_vector_type(8)));
typedef float f32x4 __attribute__((ext_vector_type(4)));

static __device__ __forceinline__ float bflo(unsigned u) {
    union { unsigned v; float f; } c; c.v = u << 16; return c.f;
}
static __device__ __forceinline__ float bfhi(unsigned u) {
    union { unsigned v; float f; } c; c.v = u & 0xffff0000u; return c.f;
}

// ---------- small prep kernels ----------

__global__ void qkern(const float* __restrict__ qe, const float* __restrict__ W,
                      const float* __restrict__ b, float* __restrict__ q) {
    int g = blockIdx.x, o = threadIdx.x;
    float s = b[o];
    for (int k = 0; k < QD; ++k) s = fmaf(qe[g * QD + k], W[k * 64 + o], s);
    q[g * 64 + o] = fmaxf(s, 0.f);
}

__global__ void convert_x(const float* __restrict__ x, __hip_bfloat16* __restrict__ xb, int n4) {
    int i = blockIdx.x * blockDim.x + threadIdx.x;
    if (i >= n4) return;
    float4 v = ((const float4*)x)[i];
    union { ushort4 u; __hip_bfloat16 h[4]; } o;
    o.h[0] = __float2bfloat16(v.x); o.h[1] = __float2bfloat16(v.y);
    o.h[2] = __float2bfloat16(v.z); o.h[3] = __float2bfloat16(v.w);
    ((ushort4*)xb)[i] = o.u;
}

// WT[n][k] bf16, n in [0,5*O): slots 0..3 = W_r columns, slot 4 = root columns
__global__ void prep_w(const float* __restrict__ W, const float* __restrict__ root,
                       __hip_bfloat16* __restrict__ WT, int O) {
    int idx = blockIdx.x * blockDim.x + threadIdx.x;
    int total = 5 * O * 128;
    if (idx >= total) return;
    int n = idx >> 7, k = idx & 127;
    float v;
    if (n < 4 * O) { int r = n / O, o = n - r * O; v = W[((size_t)r * 128 + k) * O + o]; }
    else           { int o = n - 4 * O;            v = root[(size_t)k * O + o]; }
    WT[idx] = __float2bfloat16(v);
}

// ---------- CSR build ----------

__global__ void count_edges(const int* __restrict__ dst, const int* __restrict__ et,
                            int* __restrict__ cnt) {
    int e = blockIdx.x * blockDim.x + threadIdx.x;
    if (e < EE) atomicAdd(&cnt[dst[e] * 4 + et[e]], 1);
}

__global__ void inv_deg(const int* __restrict__ cnt, float* __restrict__ inv4,
                        int* __restrict__ deg) {
    int i = blockIdx.x * blockDim.x + threadIdx.x;
    if (i >= NN) return;
    int4 c = ((const int4*)cnt)[i];
    deg[i] = c.x + c.y + c.z + c.w;
    float4 iv;
    iv.x = 1.f / fmaxf((float)c.x, 1.f);
    iv.y = 1.f / fmaxf((float)c.y, 1.f);
    iv.z = 1.f / fmaxf((float)c.z, 1.f);
    iv.w = 1.f / fmaxf((float)c.w, 1.f);
    ((float4*)inv4)[i] = iv;
}

// hierarchical scan: pass1 block sums, pass2 scan of 49 sums, pass3 write offsets+cursor
__global__ void scan_bsum(const int* __restrict__ deg, int* __restrict__ bsum) {
    __shared__ int wt[4];
    int tid = threadIdx.x, blk = blockIdx.x;
    int i0 = blk * 1024 + tid * 4;
    int s = 0;
#pragma unroll
    for (int k = 0; k < 4; ++k) { int i = i0 + k; if (i < NN) s += deg[i]; }
    for (int off = 32; off; off >>= 1) s += __shfl_down(s, off, 64);
    if ((tid & 63) == 0) wt[tid >> 6] = s;
    __syncthreads();
    if (tid == 0) bsum[blk] = wt[0] + wt[1] + wt[2] + wt[3];
}

__global__ void scan_bscan(int* __restrict__ bsum, int* __restrict__ offsets) {
    int lane = threadIdx.x;
    int v = (lane < SCAN_BLK) ? bsum[lane] : 0;
    int sc = v;
#pragma unroll
    for (int off = 1; off < 64; off <<= 1) {
        int t = __shfl_up(sc, off, 64);
        if (lane >= off) sc += t;
    }
    if (lane < SCAN_BLK) bsum[lane] = sc - v;   // exclusive
    if (lane == 0) offsets[NN] = EE;
}

__global__ void scan_write(const int* __restrict__ deg, const int* __restrict__ bsum,
                           int* __restrict__ offsets, int* __restrict__ cursor) {
    __shared__ int wtot[4];
    int tid = threadIdx.x, lane = tid & 63, w = tid >> 6, blk = blockIdx.x;
    int i0 = blk * 1024 + tid * 4;
    int v[4];
#pragma unroll
    for (int k = 0; k < 4; ++k) { int i = i0 + k; v[k] = (i < NN) ? deg[i] : 0; }
    int tsum = v[0] + v[1] + v[2] + v[3];
    int sc = tsum;
#pragma unroll
    for (int off = 1; off < 64; off <<= 1) {
        int t = __shfl_up(sc, off, 64);
        if (lane >= off) sc += t;
    }
    if (lane == 63) wtot[w] = sc;
    __syncthreads();
    int wbase = 0;
    for (int ww = 0; ww < w; ++ww) wbase += wtot[ww];
    int texcl = bsum[blk] + wbase + sc - tsum;
#pragma unroll
    for (int k = 0; k < 4; ++k) {
        int i = i0 + k;
        if (i < NN) { offsets[i] = texcl; cursor[i] = texcl; }
        texcl += v[k];
    }
}

// csr entry: (src<<2)|rel  -> directly indexes hall_b[node][rel] layout
__global__ void scatter_edges(const int* __restrict__ src, const int* __restrict__ dst,
                              const int* __restrict__ et, int* __restrict__ cursor,
                              int* __restrict__ csr) {
    int e = blockIdx.x * blockDim.x + threadIdx.x;
    if (e >= EE) return;
    int p = atomicAdd(&cursor[dst[e]], 1);
    csr[p] = (src[e] << 2) | et[e];
}

// ---------- dense: hall_b[node][rel][O] bf16 (rel transforms), hroot[node][O] fp32 ----------
// Each wave holds its 16-row A fragment in registers and sweeps ALL column
// groups, so X is read exactly once per layer (weights are L1/L2-resident).

template <int O>
__global__ __launch_bounds__(256) void dense_mm(const __hip_bfloat16* __restrict__ X,
                                                const __hip_bfloat16* __restrict__ WT,
                                                __hip_bfloat16* __restrict__ hall_b,
                                                float* __restrict__ hroot) {
    __shared__ __hip_bfloat16 tile[4][16 * 64];
    int wave = threadIdx.x >> 6;
    int lane = threadIdx.x & 63;
    int row_tile = blockIdx.x * 4 + wave;
    if (row_tile >= NN / 16) return;
    int m0 = row_tile * 16;
    int quad = lane >> 4, l15 = lane & 15;
    const __bf16* Xs = (const __bf16*)X;
    const __bf16* Ws = (const __bf16*)WT;

    bf16x8 a[4];
#pragma unroll
    for (int kk = 0; kk < 4; ++kk)
        a[kk] = *(const bf16x8*)(Xs + (size_t)(m0 + l15) * 128 + kk * 32 + quad * 8);

    constexpr int NCG = 5 * O / 64;
    __hip_bfloat16* tp = tile[wave];
    for (int cg = 0; cg < NCG; ++cg) {
        f32x4 acc[4] = {f32x4{0,0,0,0}, f32x4{0,0,0,0}, f32x4{0,0,0,0}, f32x4{0,0,0,0}};
#pragma unroll
        for (int kk = 0; kk < 4; ++kk) {
#pragma unroll
            for (int t = 0; t < 4; ++t) {
                int n = cg * 64 + t * 16 + l15;
                bf16x8 b = *(const bf16x8*)(Ws + (size_t)n * 128 + kk * 32 + quad * 8);
                acc[t] = __builtin_amdgcn_mfma_f32_16x16x32_bf16(a[kk], b, acc[t], 0, 0, 0);
            }
        }
        int slot = (O == 64) ? cg : (cg >> 1);
        int colbase = (O == 128 && (cg & 1)) ? 64 : 0;
        if (slot == 4) {
            // root: fp32 direct store
#pragma unroll
            for (int t = 0; t < 4; ++t)
#pragma unroll
                for (int reg = 0; reg < 4; ++reg) {
                    int m = m0 + quad * 4 + reg;
                    hroot[(size_t)m * O + colbase + t * 16 + l15] = acc[t][reg];
                }
        } else {
            // bf16 via LDS repack for coalesced 16B/lane stores
#pragma unroll
            for (int t = 0; t < 4; ++t)
#pragma unroll
                for (int reg = 0; reg < 4; ++reg)
                    tp[(quad * 4 + reg) * 64 + t * 16 + l15] = __float2bfloat16(acc[t][reg]);
            __builtin_amdgcn_s_waitcnt(0);  // drain own-wave LDS writes before reads
#pragma unroll
            for (int p = 0; p < 2; ++p) {
                int c = p * 64 + lane;          // 16B chunk id: row = c>>3, col0 = (c&7)*8
                int row = c >> 3, col0 = (c & 7) * 8;
                size_t off = (((size_t)(m0 + row) * 4 + slot) * O + colbase + col0) * 2;
                *(uint4*)((char*)hall_b + off) = *(uint4*)((char*)tp + c * 16);
            }
        }
    }
}

// ---------- aggregate ----------
// MODE 0: layer0 (O=64): relu, write bf16 [h | q[batch]] into xnext (128 cols)
// MODE 1: mid   (O=128): relu, write bf16 into xnext
// MODE 2: last  (O=64): no relu, write fp32 to out

template <int O, int MODE>
__global__ __launch_bounds__(256) void aggregate(const __hip_bfloat16* __restrict__ hall_b,
                                                 const float* __restrict__ hroot,
                                                 const int* __restrict__ offsets,
                                                 const int* __restrict__ csr,
                                                 const float* __restrict__ inv4,
                                                 const float* __restrict__ bias,
                                                 const float* __restrict__ q,
                                                 const int* __restrict__ batch,
                                                 __hip_bfloat16* __restrict__ xnext,
                                                 float* __restrict__ out) {
    int node = blockIdx.x * 4 + (threadIdx.x >> 6);
    int lane = threadIdx.x & 63;
    int e0 = offsets[node], e1 = offsets[node + 1];
    float4 iv = ((const float4*)inv4)[node];
    float acc0 = 0.f, acc1 = 0.f;
    const char* hb = (const char*)hall_b;
    for (int base = e0; base < e1; base += 64) {
        int e = base + lane;
        int packed = (e < e1) ? csr[e] : 0;
        int m = min(64, e1 - base);
        for (int j = 0; j < m; ++j) {
            int p = __builtin_amdgcn_readlane(packed, j);   // uniform j -> SGPR base
            int r = p & 3;
            float wgt = (r == 0) ? iv.x : (r == 1) ? iv.y : (r == 2) ? iv.z : iv.w;
            const char* hp = hb + (size_t)p * (O * 2);
            if (O == 64) {
                unsigned u = *(const unsigned short*)(hp + lane * 2);
                acc0 = fmaf(wgt, bflo(u), acc0);
            } else {
                unsigned u = *(const unsigned*)(hp + lane * 4);  // cols 2*lane, 2*lane+1
                acc0 = fmaf(wgt, bflo(u), acc0);
                acc1 = fmaf(wgt, bfhi(u), acc1);
            }
        }
    }
    if (MODE == 0) {
        float v0 = hroot[(size_t)node * 64 + lane] + bias[lane] + acc0;
        xnext[(size_t)node * 128 + lane] = __float2bfloat16(fmaxf(v0, 0.f));
        float qv = q[batch[node] * 64 + lane];
        xnext[(size_t)node * 128 + 64 + lane] = __float2bfloat16(qv);
    } else if (MODE == 1) {
        float2 rr = *(const float2*)(hroot + (size_t)node * 128 + 2 * lane);
        float2 bb = *(const float2*)(bias + 2 * lane);
        float v0 = fmaxf(rr.x + bb.x + acc0, 0.f);
        float v1 = fmaxf(rr.y + bb.y + acc1, 0.f);
        __hip_bfloat16 h0 = __float2bfloat16(v0), h1 = __float2bfloat16(v1);
        ushort2 pk;
        pk.x = *(unsigned short*)&h0; pk.y = *(unsigned short*)&h1;
        ((ushort2*)xnext)[(size_t)node * 64 + lane] = pk;
    } else {
        out[(size_t)node * 64 + lane] = hroot[(size_t)node * 64 + lane] + bias[lane] + acc0;
    }
}

// ---------- launch ----------

static inline size_t rup(size_t x) { return (x + 255) & ~(size_t)255; }

extern "C" void kernel_launch(void* const* d_in, const int* in_sizes, int n_in,
                              void* d_out, int out_size, void* d_ws, size_t ws_size,
                              hipStream_t stream) {
    const float* x      = (const float*)d_in[0];
    const int*   esrc   = (const int*)d_in[1];
    const int*   edst   = esrc + EE;
    const int*   eattr  = (const int*)d_in[2];
    const int*   batch  = (const int*)d_in[3];
    const float* qe     = (const float*)d_in[4];
    const float* qn_W   = (const float*)d_in[5];
    const float* qn_b   = (const float*)d_in[6];
    const float* W0 = (const float*)d_in[7],  *root0 = (const float*)d_in[8],  *b0 = (const float*)d_in[9];
    const float* W1 = (const float*)d_in[10], *root1 = (const float*)d_in[11], *b1 = (const float*)d_in[12];
    const float* W2 = (const float*)d_in[13], *root2 = (const float*)d_in[14], *b2 = (const float*)d_in[15];
    const float* W3 = (const float*)d_in[16], *root3 = (const float*)d_in[17], *b3 = (const float*)d_in[18];
    float* out = (float*)d_out;

    char* w = (char*)d_ws;
    float* q       = (float*)w;  w += rup(GG * 64 * 4);
    int*   cnt     = (int*)w;    w += rup((size_t)NN * 4 * 4);
    float* inv4    = (float*)w;  w += rup((size_t)NN * 4 * 4);
    int*   deg     = (int*)w;    w += rup((size_t)NN * 4);
    int*   offsets = (int*)w;    w += rup(((size_t)NN + 1) * 4);
    int*   cursor  = (int*)w;    w += rup((size_t)NN * 4);
    int*   bsum    = (int*)w;    w += rup((size_t)SCAN_BLK * 4);
    int*   csr     = (int*)w;    w += rup((size_t)EE * 4);
    __hip_bfloat16* WT0 = (__hip_bfloat16*)w; w += rup((size_t)5 * 64 * 128 * 2);
    __hip_bfloat16* WT1 = (__hip_bfloat16*)w; w += rup((size_t)5 * 128 * 128 * 2);
    __hip_bfloat16* WT2 = (__hip_bfloat16*)w; w += rup((size_t)5 * 128 * 128 * 2);
    __hip_bfloat16* WT3 = (__hip_bfloat16*)w; w += rup((size_t)5 * 64 * 128 * 2);
    __hip_bfloat16* xb0 = (__hip_bfloat16*)w; w += rup((size_t)NN * 128 * 2);
    __hip_bfloat16* xb1 = (__hip_bfloat16*)w; w += rup((size_t)NN * 128 * 2);
    __hip_bfloat16* hall_b = (__hip_bfloat16*)w; w += rup((size_t)NN * 4 * 128 * 2);
    float* hroot   = (float*)w;  w += rup((size_t)NN * 128 * 4);

    hipMemsetAsync(cnt, 0, (size_t)NN * 4 * 4, stream);

    // question projection + input conversion + weight prep
    qkern<<<GG, 64, 0, stream>>>(qe, qn_W, qn_b, q);
    convert_x<<<(NN * 128 / 4 + 255) / 256, 256, 0, stream>>>(x, xb0, NN * 128 / 4);
    prep_w<<<(5 * 64 * 128 + 255) / 256, 256, 0, stream>>>(W0, root0, WT0, 64);
    prep_w<<<(5 * 128 * 128 + 255) / 256, 256, 0, stream>>>(W1, root1, WT1, 128);
    prep_w<<<(5 * 128 * 128 + 255) / 256, 256, 0, stream>>>(W2, root2, WT2, 128);
    prep_w<<<(5 * 64 * 128 + 255) / 256, 256, 0, stream>>>(W3, root3, WT3, 64);

    // CSR build
    int eb = (EE + 255) / 256;
    count_edges<<<eb, 256, 0, stream>>>(edst, eattr, cnt);
    inv_deg<<<(NN + 255) / 256, 256, 0, stream>>>(cnt, inv4, deg);
    scan_bsum<<<SCAN_BLK, 256, 0, stream>>>(deg, bsum);
    scan_bscan<<<1, 64, 0, stream>>>(bsum, offsets);
    scan_write<<<SCAN_BLK, 256, 0, stream>>>(deg, bsum, offsets, cursor);
    scatter_edges<<<eb, 256, 0, stream>>>(esrc, edst, eattr, cursor, csr);

    int rowblk = (NN / 16 + 3) / 4;   // 782
    int aggblk = NN / 4;              // 12500

    // layer 0: x(bf16) -> hall(O=64) -> combined (xb1)
    dense_mm<64><<<rowblk, 256, 0, stream>>>(xb0, WT0, hall_b, hroot);
    aggregate<64, 0><<<aggblk, 256, 0, stream>>>(hall_b, hroot, offsets, csr, inv4, b0, q, batch, xb1, nullptr);

    // layer 1: combined -> hall(O=128) -> xb0
    dense_mm<128><<<rowblk, 256, 0, stream>>>(xb1, WT1, hall_b, hroot);
    aggregate<128, 1><<<aggblk, 256, 0, stream>>>(hall_b, hroot, offsets, csr, inv4, b1, nullptr, nullptr, xb0, nullptr);

    // layer 2: -> xb1
    dense_mm<128><<<rowblk, 256, 0, stream>>>(xb0, WT2, hall_b, hroot);
    aggregate<128, 1><<<aggblk, 256, 0, stream>>>(hall_b, hroot, offsets, csr, inv4, b2, nullptr, nullptr, xb1, nullptr);

    // layer 3: -> d_out (fp32, no relu)
    dense_mm<64><<<rowblk, 256, 0, stream>>>(xb1, WT3, hall_b, hroot);
    aggregate<64, 2><<<aggblk, 256, 0, stream>>>(hall_b, hroot, offsets, csr, inv4, b3, nullptr, nullptr, nullptr, out);
}

// Round 4
// 703.680 us; speedup vs baseline: 1.0143x; 1.0143x over previous
//
#include <hip/hip_runtime.h>
#include <hip/hip_bf16.h>

#define NN 50000
#define EE 800000
#define GG 16
#define QD 768
#define SCAN_BLK 49   // ceil(50000/1024)

typedef __bf16 bf16x8 __attribute__((ext_vector_type(8)));
typedef float f32x4 __attribute__((ext_vector_type(4)));

static __device__ __forceinline__ float bflo(unsigned u) {
    union { unsigned v; float f; } c; c.v = u << 16; return c.f;
}
static __device__ __forceinline__ float bfhi(unsigned u) {
    union { unsigned v; float f; } c; c.v = u & 0xffff0000u; return c.f;
}

// ---------- small prep kernels ----------

__global__ void qkern(const float* __restrict__ qe, const float* __restrict__ W,
                      const float* __restrict__ b, float* __restrict__ q) {
    int g = blockIdx.x, o = threadIdx.x;
    float s = b[o];
    for (int k = 0; k < QD; ++k) s = fmaf(qe[g * QD + k], W[k * 64 + o], s);
    q[g * 64 + o] = fmaxf(s, 0.f);
}

__global__ void convert_x(const float* __restrict__ x, __hip_bfloat16* __restrict__ xb, int n4) {
    int i = blockIdx.x * blockDim.x + threadIdx.x;
    if (i >= n4) return;
    float4 v = ((const float4*)x)[i];
    union { ushort4 u; __hip_bfloat16 h[4]; } o;
    o.h[0] = __float2bfloat16(v.x); o.h[1] = __float2bfloat16(v.y);
    o.h[2] = __float2bfloat16(v.z); o.h[3] = __float2bfloat16(v.w);
    ((ushort4*)xb)[i] = o.u;
}

// WT[n][k] bf16, n in [0,5*O): slots 0..3 = W_r columns, slot 4 = root columns
__global__ void prep_w(const float* __restrict__ W, const float* __restrict__ root,
                       __hip_bfloat16* __restrict__ WT, int O) {
    int idx = blockIdx.x * blockDim.x + threadIdx.x;
    int total = 5 * O * 128;
    if (idx >= total) return;
    int n = idx >> 7, k = idx & 127;
    float v;
    if (n < 4 * O) { int r = n / O, o = n - r * O; v = W[((size_t)r * 128 + k) * O + o]; }
    else           { int o = n - 4 * O;            v = root[(size_t)k * O + o]; }
    WT[idx] = __float2bfloat16(v);
}

// ---------- CSR build ----------

__global__ void count_edges(const int* __restrict__ dst, const int* __restrict__ et,
                            int* __restrict__ cnt) {
    int e = blockIdx.x * blockDim.x + threadIdx.x;
    if (e < EE) atomicAdd(&cnt[dst[e] * 4 + et[e]], 1);
}

__global__ void inv_deg(const int* __restrict__ cnt, float* __restrict__ inv4,
                        int* __restrict__ deg) {
    int i = blockIdx.x * blockDim.x + threadIdx.x;
    if (i >= NN) return;
    int4 c = ((const int4*)cnt)[i];
    deg[i] = c.x + c.y + c.z + c.w;
    float4 iv;
    iv.x = 1.f / fmaxf((float)c.x, 1.f);
    iv.y = 1.f / fmaxf((float)c.y, 1.f);
    iv.z = 1.f / fmaxf((float)c.z, 1.f);
    iv.w = 1.f / fmaxf((float)c.w, 1.f);
    ((float4*)inv4)[i] = iv;
}

// hierarchical scan: pass1 block sums, pass2 scan of 49 sums, pass3 write offsets+cursor
__global__ void scan_bsum(const int* __restrict__ deg, int* __restrict__ bsum) {
    __shared__ int wt[4];
    int tid = threadIdx.x, blk = blockIdx.x;
    int i0 = blk * 1024 + tid * 4;
    int s = 0;
#pragma unroll
    for (int k = 0; k < 4; ++k) { int i = i0 + k; if (i < NN) s += deg[i]; }
    for (int off = 32; off; off >>= 1) s += __shfl_down(s, off, 64);
    if ((tid & 63) == 0) wt[tid >> 6] = s;
    __syncthreads();
    if (tid == 0) bsum[blk] = wt[0] + wt[1] + wt[2] + wt[3];
}

__global__ void scan_bscan(int* __restrict__ bsum, int* __restrict__ offsets) {
    int lane = threadIdx.x;
    int v = (lane < SCAN_BLK) ? bsum[lane] : 0;
    int sc = v;
#pragma unroll
    for (int off = 1; off < 64; off <<= 1) {
        int t = __shfl_up(sc, off, 64);
        if (lane >= off) sc += t;
    }
    if (lane < SCAN_BLK) bsum[lane] = sc - v;   // exclusive
    if (lane == 0) offsets[NN] = EE;
}

__global__ void scan_write(const int* __restrict__ deg, const int* __restrict__ bsum,
                           int* __restrict__ offsets, int* __restrict__ cursor) {
    __shared__ int wtot[4];
    int tid = threadIdx.x, lane = tid & 63, w = tid >> 6, blk = blockIdx.x;
    int i0 = blk * 1024 + tid * 4;
    int v[4];
#pragma unroll
    for (int k = 0; k < 4; ++k) { int i = i0 + k; v[k] = (i < NN) ? deg[i] : 0; }
    int tsum = v[0] + v[1] + v[2] + v[3];
    int sc = tsum;
#pragma unroll
    for (int off = 1; off < 64; off <<= 1) {
        int t = __shfl_up(sc, off, 64);
        if (lane >= off) sc += t;
    }
    if (lane == 63) wtot[w] = sc;
    __syncthreads();
    int wbase = 0;
    for (int ww = 0; ww < w; ++ww) wbase += wtot[ww];
    int texcl = bsum[blk] + wbase + sc - tsum;
#pragma unroll
    for (int k = 0; k < 4; ++k) {
        int i = i0 + k;
        if (i < NN) { offsets[i] = texcl; cursor[i] = texcl; }
        texcl += v[k];
    }
}

// csr entry: (src<<2)|rel  -> directly indexes hall_b[node][rel] layout
__global__ void scatter_edges(const int* __restrict__ src, const int* __restrict__ dst,
                              const int* __restrict__ et, int* __restrict__ cursor,
                              int* __restrict__ csr) {
    int e = blockIdx.x * blockDim.x + threadIdx.x;
    if (e >= EE) return;
    int p = atomicAdd(&cursor[dst[e]], 1);
    csr[p] = (src[e] << 2) | et[e];
}

// ---------- dense: hall_b[node][rel][O] bf16 (rel transforms), hroot[node][O] fp32 ----------
// MFMA operands SWAPPED (A=W, B=X): D col(lane&15)=node, row(quad*4+reg)=out col.
// Each lane holds 4 consecutive output cols of one node -> direct packed stores,
// no LDS repack. X fragment loaded once per wave; cg sweep split over gridDim.y.

template <int O>
__global__ __launch_bounds__(256) void dense_mm(const __hip_bfloat16* __restrict__ X,
                                                const __hip_bfloat16* __restrict__ WT,
                                                __hip_bfloat16* __restrict__ hall_b,
                                                float* __restrict__ hroot) {
    int wave = threadIdx.x >> 6;
    int lane = threadIdx.x & 63;
    int row_tile = blockIdx.x * 4 + wave;
    if (row_tile >= NN / 16) return;
    int m0 = row_tile * 16;
    int quad = lane >> 4, l15 = lane & 15;
    const __bf16* Xs = (const __bf16*)X;
    const __bf16* Ws = (const __bf16*)WT;

    bf16x8 a[4];
#pragma unroll
    for (int kk = 0; kk < 4; ++kk)
        a[kk] = *(const bf16x8*)(Xs + (size_t)(m0 + l15) * 128 + kk * 32 + quad * 8);

    int cg0, cg1;
    if (O == 128) { cg0 = blockIdx.y * 5; cg1 = cg0 + 5; }
    else          { cg0 = blockIdx.y ? 3 : 0; cg1 = blockIdx.y ? 5 : 3; }

    int node = m0 + l15;
    for (int cg = cg0; cg < cg1; ++cg) {
        f32x4 acc[4] = {f32x4{0,0,0,0}, f32x4{0,0,0,0}, f32x4{0,0,0,0}, f32x4{0,0,0,0}};
#pragma unroll
        for (int kk = 0; kk < 4; ++kk) {
#pragma unroll
            for (int t = 0; t < 4; ++t) {
                int n = cg * 64 + t * 16 + l15;
                bf16x8 b = *(const bf16x8*)(Ws + (size_t)n * 128 + kk * 32 + quad * 8);
                // A = W fragment, B = X fragment  (transposed output layout)
                acc[t] = __builtin_amdgcn_mfma_f32_16x16x32_bf16(b, a[kk], acc[t], 0, 0, 0);
            }
        }
        int slot = (O == 64) ? cg : (cg >> 1);
        int colbase = (O == 128 && (cg & 1)) ? 64 : 0;
        if (slot == 4) {
#pragma unroll
            for (int t = 0; t < 4; ++t)
                *(f32x4*)&hroot[(size_t)node * O + colbase + t * 16 + quad * 4] = acc[t];
        } else {
#pragma unroll
            for (int t = 0; t < 4; ++t) {
                union { ushort4 u; __hip_bfloat16 h[4]; } pk;
#pragma unroll
                for (int reg = 0; reg < 4; ++reg) pk.h[reg] = __float2bfloat16(acc[t][reg]);
                *(ushort4*)&hall_b[((size_t)node * 4 + slot) * O + colbase + t * 16 + quad * 4] = pk.u;
            }
        }
    }
}

// ---------- aggregate ----------
// MODE 0: layer0 (O=64): relu, write bf16 [h | q[batch]] into xnext (128 cols)
// MODE 1: mid   (O=128): relu, write bf16 into xnext
// MODE 2: last  (O=64): no relu, write fp32 to out

template <int O, int MODE>
__global__ __launch_bounds__(256) void aggregate(const __hip_bfloat16* __restrict__ hall_b,
                                                 const float* __restrict__ hroot,
                                                 const int* __restrict__ offsets,
                                                 const int* __restrict__ csr,
                                                 const float* __restrict__ inv4,
                                                 const float* __restrict__ bias,
                                                 const float* __restrict__ q,
                                                 const int* __restrict__ batch,
                                                 __hip_bfloat16* __restrict__ xnext,
                                                 float* __restrict__ out) {
    int node = blockIdx.x * 4 + (threadIdx.x >> 6);
    int lane = threadIdx.x & 63;
    int e0 = offsets[node], e1 = offsets[node + 1];
    float4 iv = ((const float4*)inv4)[node];
    float acc0 = 0.f, acc1 = 0.f;
    const char* hb = (const char*)hall_b;
    for (int base = e0; base < e1; base += 64) {
        int e = base + lane;
        int packed = (e < e1) ? csr[e] : 0;
        int m = min(64, e1 - base);
        for (int j = 0; j < m; ++j) {
            int p = __builtin_amdgcn_readlane(packed, j);   // uniform j -> SGPR base
            int r = p & 3;
            float wgt = (r == 0) ? iv.x : (r == 1) ? iv.y : (r == 2) ? iv.z : iv.w;
            const char* hp = hb + (size_t)p * (O * 2);
            if (O == 64) {
                unsigned u = *(const unsigned short*)(hp + lane * 2);
                acc0 = fmaf(wgt, bflo(u), acc0);
            } else {
                unsigned u = *(const unsigned*)(hp + lane * 4);  // cols 2*lane, 2*lane+1
                acc0 = fmaf(wgt, bflo(u), acc0);
                acc1 = fmaf(wgt, bfhi(u), acc1);
            }
        }
    }
    if (MODE == 0) {
        float v0 = hroot[(size_t)node * 64 + lane] + bias[lane] + acc0;
        xnext[(size_t)node * 128 + lane] = __float2bfloat16(fmaxf(v0, 0.f));
        float qv = q[batch[node] * 64 + lane];
        xnext[(size_t)node * 128 + 64 + lane] = __float2bfloat16(qv);
    } else if (MODE == 1) {
        float2 rr = *(const float2*)(hroot + (size_t)node * 128 + 2 * lane);
        float2 bb = *(const float2*)(bias + 2 * lane);
        float v0 = fmaxf(rr.x + bb.x + acc0, 0.f);
        float v1 = fmaxf(rr.y + bb.y + acc1, 0.f);
        __hip_bfloat16 h0 = __float2bfloat16(v0), h1 = __float2bfloat16(v1);
        ushort2 pk;
        pk.x = *(unsigned short*)&h0; pk.y = *(unsigned short*)&h1;
        ((ushort2*)xnext)[(size_t)node * 64 + lane] = pk;
    } else {
        out[(size_t)node * 64 + lane] = hroot[(size_t)node * 64 + lane] + bias[lane] + acc0;
    }
}

// ---------- launch ----------

static inline size_t rup(size_t x) { return (x + 255) & ~(size_t)255; }

extern "C" void kernel_launch(void* const* d_in, const int* in_sizes, int n_in,
                              void* d_out, int out_size, void* d_ws, size_t ws_size,
                              hipStream_t stream) {
    const float* x      = (const float*)d_in[0];
    const int*   esrc   = (const int*)d_in[1];
    const int*   edst   = esrc + EE;
    const int*   eattr  = (const int*)d_in[2];
    const int*   batch  = (const int*)d_in[3];
    const float* qe     = (const float*)d_in[4];
    const float* qn_W   = (const float*)d_in[5];
    const float* qn_b   = (const float*)d_in[6];
    const float* W0 = (const float*)d_in[7],  *root0 = (const float*)d_in[8],  *b0 = (const float*)d_in[9];
    const float* W1 = (const float*)d_in[10], *root1 = (const float*)d_in[11], *b1 = (const float*)d_in[12];
    const float* W2 = (const float*)d_in[13], *root2 = (const float*)d_in[14], *b2 = (const float*)d_in[15];
    const float* W3 = (const float*)d_in[16], *root3 = (const float*)d_in[17], *b3 = (const float*)d_in[18];
    float* out = (float*)d_out;

    char* w = (char*)d_ws;
    float* q       = (float*)w;  w += rup(GG * 64 * 4);
    int*   cnt     = (int*)w;    w += rup((size_t)NN * 4 * 4);
    float* inv4    = (float*)w;  w += rup((size_t)NN * 4 * 4);
    int*   deg     = (int*)w;    w += rup((size_t)NN * 4);
    int*   offsets = (int*)w;    w += rup(((size_t)NN + 1) * 4);
    int*   cursor  = (int*)w;    w += rup((size_t)NN * 4);
    int*   bsum    = (int*)w;    w += rup((size_t)SCAN_BLK * 4);
    int*   csr     = (int*)w;    w += rup((size_t)EE * 4);
    __hip_bfloat16* WT0 = (__hip_bfloat16*)w; w += rup((size_t)5 * 64 * 128 * 2);
    __hip_bfloat16* WT1 = (__hip_bfloat16*)w; w += rup((size_t)5 * 128 * 128 * 2);
    __hip_bfloat16* WT2 = (__hip_bfloat16*)w; w += rup((size_t)5 * 128 * 128 * 2);
    __hip_bfloat16* WT3 = (__hip_bfloat16*)w; w += rup((size_t)5 * 64 * 128 * 2);
    __hip_bfloat16* xb0 = (__hip_bfloat16*)w; w += rup((size_t)NN * 128 * 2);
    __hip_bfloat16* xb1 = (__hip_bfloat16*)w; w += rup((size_t)NN * 128 * 2);
    __hip_bfloat16* hall_b = (__hip_bfloat16*)w; w += rup((size_t)NN * 4 * 128 * 2);
    float* hroot   = (float*)w;  w += rup((size_t)NN * 128 * 4);

    hipMemsetAsync(cnt, 0, (size_t)NN * 4 * 4, stream);

    // question projection + input conversion + weight prep
    qkern<<<GG, 64, 0, stream>>>(qe, qn_W, qn_b, q);
    convert_x<<<(NN * 128 / 4 + 255) / 256, 256, 0, stream>>>(x, xb0, NN * 128 / 4);
    prep_w<<<(5 * 64 * 128 + 255) / 256, 256, 0, stream>>>(W0, root0, WT0, 64);
    prep_w<<<(5 * 128 * 128 + 255) / 256, 256, 0, stream>>>(W1, root1, WT1, 128);
    prep_w<<<(5 * 128 * 128 + 255) / 256, 256, 0, stream>>>(W2, root2, WT2, 128);
    prep_w<<<(5 * 64 * 128 + 255) / 256, 256, 0, stream>>>(W3, root3, WT3, 64);

    // CSR build
    int eb = (EE + 255) / 256;
    count_edges<<<eb, 256, 0, stream>>>(edst, eattr, cnt);
    inv_deg<<<(NN + 255) / 256, 256, 0, stream>>>(cnt, inv4, deg);
    scan_bsum<<<SCAN_BLK, 256, 0, stream>>>(deg, bsum);
    scan_bscan<<<1, 64, 0, stream>>>(bsum, offsets);
    scan_write<<<SCAN_BLK, 256, 0, stream>>>(deg, bsum, offsets, cursor);
    scatter_edges<<<eb, 256, 0, stream>>>(esrc, edst, eattr, cursor, csr);

    int rowblk = (NN / 16 + 3) / 4;   // 782
    int aggblk = NN / 4;              // 12500

    // layer 0: x(bf16) -> hall(O=64) -> combined (xb1)
    dense_mm<64><<<dim3(rowblk, 2), 256, 0, stream>>>(xb0, WT0, hall_b, hroot);
    aggregate<64, 0><<<aggblk, 256, 0, stream>>>(hall_b, hroot, offsets, csr, inv4, b0, q, batch, xb1, nullptr);

    // layer 1: combined -> hall(O=128) -> xb0
    dense_mm<128><<<dim3(rowblk, 2), 256, 0, stream>>>(xb1, WT1, hall_b, hroot);
    aggregate<128, 1><<<aggblk, 256, 0, stream>>>(hall_b, hroot, offsets, csr, inv4, b1, nullptr, nullptr, xb0, nullptr);

    // layer 2: -> xb1
    dense_mm<128><<<dim3(rowblk, 2), 256, 0, stream>>>(xb0, WT2, hall_b, hroot);
    aggregate<128, 1><<<aggblk, 256, 0, stream>>>(hall_b, hroot, offsets, csr, inv4, b2, nullptr, nullptr, xb1, nullptr);

    // layer 3: -> d_out (fp32, no relu)
    dense_mm<64><<<dim3(rowblk, 2), 256, 0, stream>>>(xb1, WT3, hall_b, hroot);
    aggregate<64, 2><<<aggblk, 256, 0, stream>>>(hall_b, hroot, offsets, csr, inv4, b3, nullptr, nullptr, nullptr, out);
}

// Round 5
// 590.580 us; speedup vs baseline: 1.2086x; 1.1915x over previous
//
#include <hip/hip_runtime.h>
#include <hip/hip_bf16.h>

#define NN 50000
#define EE 800000
#define GG 16
#define QD 768
#define SCAN_BLK 49   // ceil(50000/1024)

typedef __bf16 bf16x8 __attribute__((ext_vector_type(8)));
typedef float f32x4 __attribute__((ext_vector_type(4)));

static __device__ __forceinline__ float bflo(unsigned u) {
    union { unsigned v; float f; } c; c.v = u << 16; return c.f;
}
static __device__ __forceinline__ float bfhi(unsigned u) {
    union { unsigned v; float f; } c; c.v = u & 0xffff0000u; return c.f;
}

// ---------- small prep kernels ----------

__global__ void qkern(const float* __restrict__ qe, const float* __restrict__ W,
                      const float* __restrict__ b, float* __restrict__ q) {
    int g = blockIdx.x, o = threadIdx.x;
    float s = b[o];
    for (int k = 0; k < QD; ++k) s = fmaf(qe[g * QD + k], W[k * 64 + o], s);
    q[g * 64 + o] = fmaxf(s, 0.f);
}

__global__ void convert_x(const float* __restrict__ x, __hip_bfloat16* __restrict__ xb, int n4) {
    int i = blockIdx.x * blockDim.x + threadIdx.x;
    if (i >= n4) return;
    float4 v = ((const float4*)x)[i];
    union { ushort4 u; __hip_bfloat16 h[4]; } o;
    o.h[0] = __float2bfloat16(v.x); o.h[1] = __float2bfloat16(v.y);
    o.h[2] = __float2bfloat16(v.z); o.h[3] = __float2bfloat16(v.w);
    ((ushort4*)xb)[i] = o.u;
}

// WT[n][k] bf16, n in [0,5*O): slots 0..3 = W_r columns, slot 4 = root columns
__global__ void prep_w(const float* __restrict__ W, const float* __restrict__ root,
                       __hip_bfloat16* __restrict__ WT, int O) {
    int idx = blockIdx.x * blockDim.x + threadIdx.x;
    int total = 5 * O * 128;
    if (idx >= total) return;
    int n = idx >> 7, k = idx & 127;
    float v;
    if (n < 4 * O) { int r = n / O, o = n - r * O; v = W[((size_t)r * 128 + k) * O + o]; }
    else           { int o = n - 4 * O;            v = root[(size_t)k * O + o]; }
    WT[idx] = __float2bfloat16(v);
}

// ---------- CSR build ----------

__global__ void count_edges(const int* __restrict__ dst, const int* __restrict__ et,
                            int* __restrict__ cnt) {
    int e = blockIdx.x * blockDim.x + threadIdx.x;
    if (e < EE) atomicAdd(&cnt[dst[e] * 4 + et[e]], 1);
}

__global__ void inv_deg(const int* __restrict__ cnt, float* __restrict__ inv4,
                        int* __restrict__ deg) {
    int i = blockIdx.x * blockDim.x + threadIdx.x;
    if (i >= NN) return;
    int4 c = ((const int4*)cnt)[i];
    deg[i] = c.x + c.y + c.z + c.w;
    float4 iv;
    iv.x = 1.f / fmaxf((float)c.x, 1.f);
    iv.y = 1.f / fmaxf((float)c.y, 1.f);
    iv.z = 1.f / fmaxf((float)c.z, 1.f);
    iv.w = 1.f / fmaxf((float)c.w, 1.f);
    ((float4*)inv4)[i] = iv;
}

// hierarchical scan: pass1 block sums, pass2 scan of 49 sums, pass3 write offsets+cursor
__global__ void scan_bsum(const int* __restrict__ deg, int* __restrict__ bsum) {
    __shared__ int wt[4];
    int tid = threadIdx.x, blk = blockIdx.x;
    int i0 = blk * 1024 + tid * 4;
    int s = 0;
#pragma unroll
    for (int k = 0; k < 4; ++k) { int i = i0 + k; if (i < NN) s += deg[i]; }
    for (int off = 32; off; off >>= 1) s += __shfl_down(s, off, 64);
    if ((tid & 63) == 0) wt[tid >> 6] = s;
    __syncthreads();
    if (tid == 0) bsum[blk] = wt[0] + wt[1] + wt[2] + wt[3];
}

__global__ void scan_bscan(int* __restrict__ bsum, int* __restrict__ offsets) {
    int lane = threadIdx.x;
    int v = (lane < SCAN_BLK) ? bsum[lane] : 0;
    int sc = v;
#pragma unroll
    for (int off = 1; off < 64; off <<= 1) {
        int t = __shfl_up(sc, off, 64);
        if (lane >= off) sc += t;
    }
    if (lane < SCAN_BLK) bsum[lane] = sc - v;   // exclusive
    if (lane == 0) offsets[NN] = EE;
}

__global__ void scan_write(const int* __restrict__ deg, const int* __restrict__ bsum,
                           int* __restrict__ offsets, int* __restrict__ cursor) {
    __shared__ int wtot[4];
    int tid = threadIdx.x, lane = tid & 63, w = tid >> 6, blk = blockIdx.x;
    int i0 = blk * 1024 + tid * 4;
    int v[4];
#pragma unroll
    for (int k = 0; k < 4; ++k) { int i = i0 + k; v[k] = (i < NN) ? deg[i] : 0; }
    int tsum = v[0] + v[1] + v[2] + v[3];
    int sc = tsum;
#pragma unroll
    for (int off = 1; off < 64; off <<= 1) {
        int t = __shfl_up(sc, off, 64);
        if (lane >= off) sc += t;
    }
    if (lane == 63) wtot[w] = sc;
    __syncthreads();
    int wbase = 0;
    for (int ww = 0; ww < w; ++ww) wbase += wtot[ww];
    int texcl = bsum[blk] + wbase + sc - tsum;
#pragma unroll
    for (int k = 0; k < 4; ++k) {
        int i = i0 + k;
        if (i < NN) { offsets[i] = texcl; cursor[i] = texcl; }
        texcl += v[k];
    }
}

// csr entry: (src<<2)|rel  -> directly indexes hall_b[node][rel] layout
__global__ void scatter_edges(const int* __restrict__ src, const int* __restrict__ dst,
                              const int* __restrict__ et, int* __restrict__ cursor,
                              int* __restrict__ csr) {
    int e = blockIdx.x * blockDim.x + threadIdx.x;
    if (e >= EE) return;
    int p = atomicAdd(&cursor[dst[e]], 1);
    csr[p] = (src[e] << 2) | et[e];
}

// ---------- dense: hall_b[node][rel][O] bf16 (rel transforms), hroot[node][O] fp32 ----------
// Unswapped MFMA (A=X rows, B=W cols): D col=l15 -> out col, (quad,reg) -> node row.
// ALL outputs round-trip a per-wave LDS tile so global stores are fully
// coalesced (8-16 whole cache lines per store instruction). No explicit
// waitcnt: compiler inserts lgkmcnt-only waits for the LDS RAW/WAR deps.

template <int O>
__global__ __launch_bounds__(256) void dense_mm(const __hip_bfloat16* __restrict__ X,
                                                const __hip_bfloat16* __restrict__ WT,
                                                __hip_bfloat16* __restrict__ hall_b,
                                                float* __restrict__ hroot) {
    __shared__ char tilebuf[4][4096];   // per-wave: 16x64 fp32 (4KB) or 16x64 bf16 (2KB)
    int wave = threadIdx.x >> 6;
    int lane = threadIdx.x & 63;
    int row_tile = blockIdx.x * 4 + wave;
    if (row_tile >= NN / 16) return;
    int m0 = row_tile * 16;
    int quad = lane >> 4, l15 = lane & 15;
    const __bf16* Xs = (const __bf16*)X;
    const __bf16* Ws = (const __bf16*)WT;

    bf16x8 a[4];
#pragma unroll
    for (int kk = 0; kk < 4; ++kk)
        a[kk] = *(const bf16x8*)(Xs + (size_t)(m0 + l15) * 128 + kk * 32 + quad * 8);

    int cg0, cg1;
    if (O == 128) { cg0 = blockIdx.y * 5; cg1 = cg0 + 5; }
    else          { cg0 = blockIdx.y ? 3 : 0; cg1 = blockIdx.y ? 5 : 3; }

    for (int cg = cg0; cg < cg1; ++cg) {
        f32x4 acc[4] = {f32x4{0,0,0,0}, f32x4{0,0,0,0}, f32x4{0,0,0,0}, f32x4{0,0,0,0}};
#pragma unroll
        for (int kk = 0; kk < 4; ++kk) {
#pragma unroll
            for (int t = 0; t < 4; ++t) {
                int n = cg * 64 + t * 16 + l15;
                bf16x8 b = *(const bf16x8*)(Ws + (size_t)n * 128 + kk * 32 + quad * 8);
                acc[t] = __builtin_amdgcn_mfma_f32_16x16x32_bf16(a[kk], b, acc[t], 0, 0, 0);
            }
        }
        int slot = (O == 64) ? cg : (cg >> 1);
        int colbase = (O == 128 && (cg & 1)) ? 64 : 0;
        if (slot == 4) {
            // root fp32: repack 16x64 f32 tile -> 16B/lane coalesced stores
            float* tp = (float*)tilebuf[wave];
#pragma unroll
            for (int t = 0; t < 4; ++t)
#pragma unroll
                for (int reg = 0; reg < 4; ++reg)
                    tp[(quad * 4 + reg) * 64 + t * 16 + l15] = acc[t][reg];
#pragma unroll
            for (int p = 0; p < 4; ++p) {
                int c = p * 64 + lane;          // 16B chunk: row = c>>4, col0 = (c&15)*4
                int row = c >> 4, col0 = (c & 15) * 4;
                *(f32x4*)&hroot[(size_t)(m0 + row) * O + colbase + col0] =
                    ((const f32x4*)tp)[c];
            }
        } else {
            // bf16: repack 16x64 bf16 tile -> 16B/lane coalesced stores
            __hip_bfloat16* tp = (__hip_bfloat16*)tilebuf[wave];
#pragma unroll
            for (int t = 0; t < 4; ++t)
#pragma unroll
                for (int reg = 0; reg < 4; ++reg)
                    tp[(quad * 4 + reg) * 64 + t * 16 + l15] = __float2bfloat16(acc[t][reg]);
#pragma unroll
            for (int p = 0; p < 2; ++p) {
                int c = p * 64 + lane;          // 16B chunk: row = c>>3, col0 = (c&7)*8
                int row = c >> 3, col0 = (c & 7) * 8;
                *(uint4*)&hall_b[((size_t)(m0 + row) * 4 + slot) * O + colbase + col0] =
                    ((const uint4*)tp)[c];
            }
        }
    }
}

// ---------- aggregate ----------
// MODE 0: layer0 (O=64): relu, write bf16 [h | q[batch]] into xnext (128 cols)
// MODE 1: mid   (O=128): relu, write bf16 into xnext
// MODE 2: last  (O=64): no relu, write fp32 to out

template <int O, int MODE>
__global__ __launch_bounds__(256) void aggregate(const __hip_bfloat16* __restrict__ hall_b,
                                                 const float* __restrict__ hroot,
                                                 const int* __restrict__ offsets,
                                                 const int* __restrict__ csr,
                                                 const float* __restrict__ inv4,
                                                 const float* __restrict__ bias,
                                                 const float* __restrict__ q,
                                                 const int* __restrict__ batch,
                                                 __hip_bfloat16* __restrict__ xnext,
                                                 float* __restrict__ out) {
    int node = blockIdx.x * 4 + (threadIdx.x >> 6);
    int lane = threadIdx.x & 63;
    int e0 = offsets[node], e1 = offsets[node + 1];
    float4 iv = ((const float4*)inv4)[node];
    float acc0 = 0.f, acc1 = 0.f;
    const char* hb = (const char*)hall_b;
    for (int base = e0; base < e1; base += 64) {
        int e = base + lane;
        int packed = (e < e1) ? csr[e] : 0;
        int m = min(64, e1 - base);
        int j = 0;
        // 4x unrolled: 4 independent gather loads in flight
        for (; j + 4 <= m; j += 4) {
            int p0 = __builtin_amdgcn_readlane(packed, j);
            int p1 = __builtin_amdgcn_readlane(packed, j + 1);
            int p2 = __builtin_amdgcn_readlane(packed, j + 2);
            int p3 = __builtin_amdgcn_readlane(packed, j + 3);
            int r0 = p0 & 3, r1 = p1 & 3, r2 = p2 & 3, r3 = p3 & 3;
            float w0 = (r0 == 0) ? iv.x : (r0 == 1) ? iv.y : (r0 == 2) ? iv.z : iv.w;
            float w1 = (r1 == 0) ? iv.x : (r1 == 1) ? iv.y : (r1 == 2) ? iv.z : iv.w;
            float w2 = (r2 == 0) ? iv.x : (r2 == 1) ? iv.y : (r2 == 2) ? iv.z : iv.w;
            float w3 = (r3 == 0) ? iv.x : (r3 == 1) ? iv.y : (r3 == 2) ? iv.z : iv.w;
            if (O == 64) {
                unsigned u0 = *(const unsigned short*)(hb + (size_t)p0 * 128 + lane * 2);
                unsigned u1 = *(const unsigned short*)(hb + (size_t)p1 * 128 + lane * 2);
                unsigned u2 = *(const unsigned short*)(hb + (size_t)p2 * 128 + lane * 2);
                unsigned u3 = *(const unsigned short*)(hb + (size_t)p3 * 128 + lane * 2);
                acc0 = fmaf(w0, bflo(u0), acc0);
                acc0 = fmaf(w1, bflo(u1), acc0);
                acc0 = fmaf(w2, bflo(u2), acc0);
                acc0 = fmaf(w3, bflo(u3), acc0);
            } else {
                unsigned u0 = *(const unsigned*)(hb + (size_t)p0 * 256 + lane * 4);
                unsigned u1 = *(const unsigned*)(hb + (size_t)p1 * 256 + lane * 4);
                unsigned u2 = *(const unsigned*)(hb + (size_t)p2 * 256 + lane * 4);
                unsigned u3 = *(const unsigned*)(hb + (size_t)p3 * 256 + lane * 4);
                acc0 = fmaf(w0, bflo(u0), acc0);  acc1 = fmaf(w0, bfhi(u0), acc1);
                acc0 = fmaf(w1, bflo(u1), acc0);  acc1 = fmaf(w1, bfhi(u1), acc1);
                acc0 = fmaf(w2, bflo(u2), acc0);  acc1 = fmaf(w2, bfhi(u2), acc1);
                acc0 = fmaf(w3, bflo(u3), acc0);  acc1 = fmaf(w3, bfhi(u3), acc1);
            }
        }
        for (; j < m; ++j) {
            int p = __builtin_amdgcn_readlane(packed, j);
            int r = p & 3;
            float wgt = (r == 0) ? iv.x : (r == 1) ? iv.y : (r == 2) ? iv.z : iv.w;
            if (O == 64) {
                unsigned u = *(const unsigned short*)(hb + (size_t)p * 128 + lane * 2);
                acc0 = fmaf(wgt, bflo(u), acc0);
            } else {
                unsigned u = *(const unsigned*)(hb + (size_t)p * 256 + lane * 4);
                acc0 = fmaf(wgt, bflo(u), acc0);
                acc1 = fmaf(wgt, bfhi(u), acc1);
            }
        }
    }
    if (MODE == 0) {
        float v0 = hroot[(size_t)node * 64 + lane] + bias[lane] + acc0;
        xnext[(size_t)node * 128 + lane] = __float2bfloat16(fmaxf(v0, 0.f));
        float qv = q[batch[node] * 64 + lane];
        xnext[(size_t)node * 128 + 64 + lane] = __float2bfloat16(qv);
    } else if (MODE == 1) {
        float2 rr = *(const float2*)(hroot + (size_t)node * 128 + 2 * lane);
        float2 bb = *(const float2*)(bias + 2 * lane);
        float v0 = fmaxf(rr.x + bb.x + acc0, 0.f);
        float v1 = fmaxf(rr.y + bb.y + acc1, 0.f);
        __hip_bfloat16 h0 = __float2bfloat16(v0), h1 = __float2bfloat16(v1);
        ushort2 pk;
        pk.x = *(unsigned short*)&h0; pk.y = *(unsigned short*)&h1;
        ((ushort2*)xnext)[(size_t)node * 64 + lane] = pk;
    } else {
        out[(size_t)node * 64 + lane] = hroot[(size_t)node * 64 + lane] + bias[lane] + acc0;
    }
}

// ---------- launch ----------

static inline size_t rup(size_t x) { return (x + 255) & ~(size_t)255; }

extern "C" void kernel_launch(void* const* d_in, const int* in_sizes, int n_in,
                              void* d_out, int out_size, void* d_ws, size_t ws_size,
                              hipStream_t stream) {
    const float* x      = (const float*)d_in[0];
    const int*   esrc   = (const int*)d_in[1];
    const int*   edst   = esrc + EE;
    const int*   eattr  = (const int*)d_in[2];
    const int*   batch  = (const int*)d_in[3];
    const float* qe     = (const float*)d_in[4];
    const float* qn_W   = (const float*)d_in[5];
    const float* qn_b   = (const float*)d_in[6];
    const float* W0 = (const float*)d_in[7],  *root0 = (const float*)d_in[8],  *b0 = (const float*)d_in[9];
    const float* W1 = (const float*)d_in[10], *root1 = (const float*)d_in[11], *b1 = (const float*)d_in[12];
    const float* W2 = (const float*)d_in[13], *root2 = (const float*)d_in[14], *b2 = (const float*)d_in[15];
    const float* W3 = (const float*)d_in[16], *root3 = (const float*)d_in[17], *b3 = (const float*)d_in[18];
    float* out = (float*)d_out;

    char* w = (char*)d_ws;
    float* q       = (float*)w;  w += rup(GG * 64 * 4);
    int*   cnt     = (int*)w;    w += rup((size_t)NN * 4 * 4);
    float* inv4    = (float*)w;  w += rup((size_t)NN * 4 * 4);
    int*   deg     = (int*)w;    w += rup((size_t)NN * 4);
    int*   offsets = (int*)w;    w += rup(((size_t)NN + 1) * 4);
    int*   cursor  = (int*)w;    w += rup((size_t)NN * 4);
    int*   bsum    = (int*)w;    w += rup((size_t)SCAN_BLK * 4);
    int*   csr     = (int*)w;    w += rup((size_t)EE * 4);
    __hip_bfloat16* WT0 = (__hip_bfloat16*)w; w += rup((size_t)5 * 64 * 128 * 2);
    __hip_bfloat16* WT1 = (__hip_bfloat16*)w; w += rup((size_t)5 * 128 * 128 * 2);
    __hip_bfloat16* WT2 = (__hip_bfloat16*)w; w += rup((size_t)5 * 128 * 128 * 2);
    __hip_bfloat16* WT3 = (__hip_bfloat16*)w; w += rup((size_t)5 * 64 * 128 * 2);
    __hip_bfloat16* xb0 = (__hip_bfloat16*)w; w += rup((size_t)NN * 128 * 2);
    __hip_bfloat16* xb1 = (__hip_bfloat16*)w; w += rup((size_t)NN * 128 * 2);
    __hip_bfloat16* hall_b = (__hip_bfloat16*)w; w += rup((size_t)NN * 4 * 128 * 2);
    float* hroot   = (float*)w;  w += rup((size_t)NN * 128 * 4);

    hipMemsetAsync(cnt, 0, (size_t)NN * 4 * 4, stream);

    // question projection + input conversion + weight prep
    qkern<<<GG, 64, 0, stream>>>(qe, qn_W, qn_b, q);
    convert_x<<<(NN * 128 / 4 + 255) / 256, 256, 0, stream>>>(x, xb0, NN * 128 / 4);
    prep_w<<<(5 * 64 * 128 + 255) / 256, 256, 0, stream>>>(W0, root0, WT0, 64);
    prep_w<<<(5 * 128 * 128 + 255) / 256, 256, 0, stream>>>(W1, root1, WT1, 128);
    prep_w<<<(5 * 128 * 128 + 255) / 256, 256, 0, stream>>>(W2, root2, WT2, 128);
    prep_w<<<(5 * 64 * 128 + 255) / 256, 256, 0, stream>>>(W3, root3, WT3, 64);

    // CSR build
    int eb = (EE + 255) / 256;
    count_edges<<<eb, 256, 0, stream>>>(edst, eattr, cnt);
    inv_deg<<<(NN + 255) / 256, 256, 0, stream>>>(cnt, inv4, deg);
    scan_bsum<<<SCAN_BLK, 256, 0, stream>>>(deg, bsum);
    scan_bscan<<<1, 64, 0, stream>>>(bsum, offsets);
    scan_write<<<SCAN_BLK, 256, 0, stream>>>(deg, bsum, offsets, cursor);
    scatter_edges<<<eb, 256, 0, stream>>>(esrc, edst, eattr, cursor, csr);

    int rowblk = (NN / 16 + 3) / 4;   // 782
    int aggblk = NN / 4;              // 12500

    // layer 0: x(bf16) -> hall(O=64) -> combined (xb1)
    dense_mm<64><<<dim3(rowblk, 2), 256, 0, stream>>>(xb0, WT0, hall_b, hroot);
    aggregate<64, 0><<<aggblk, 256, 0, stream>>>(hall_b, hroot, offsets, csr, inv4, b0, q, batch, xb1, nullptr);

    // layer 1: combined -> hall(O=128) -> xb0
    dense_mm<128><<<dim3(rowblk, 2), 256, 0, stream>>>(xb1, WT1, hall_b, hroot);
    aggregate<128, 1><<<aggblk, 256, 0, stream>>>(hall_b, hroot, offsets, csr, inv4, b1, nullptr, nullptr, xb0, nullptr);

    // layer 2: -> xb1
    dense_mm<128><<<dim3(rowblk, 2), 256, 0, stream>>>(xb0, WT2, hall_b, hroot);
    aggregate<128, 1><<<aggblk, 256, 0, stream>>>(hall_b, hroot, offsets, csr, inv4, b2, nullptr, nullptr, xb1, nullptr);

    // layer 3: -> d_out (fp32, no relu)
    dense_mm<64><<<dim3(rowblk, 2), 256, 0, stream>>>(xb1, WT3, hall_b, hroot);
    aggregate<64, 2><<<aggblk, 256, 0, stream>>>(hall_b, hroot, offsets, csr, inv4, b3, nullptr, nullptr, nullptr, out);
}

// Round 6
// 488.799 us; speedup vs baseline: 1.4602x; 1.2082x over previous
//
#include <hip/hip_runtime.h>
#include <hip/hip_bf16.h>

#define NN 50000
#define EE 800000
#define GG 16
#define QD 768
#define SCAN_BLK 49   // ceil(50000/1024)

typedef __bf16 bf16x8 __attribute__((ext_vector_type(8)));
typedef float f32x4 __attribute__((ext_vector_type(4)));

static __device__ __forceinline__ float bflo(unsigned u) {
    union { unsigned v; float f; } c; c.v = u << 16; return c.f;
}
static __device__ __forceinline__ float bfhi(unsigned u) {
    union { unsigned v; float f; } c; c.v = u & 0xffff0000u; return c.f;
}

// ---------- small prep kernels ----------

__global__ void qkern(const float* __restrict__ qe, const float* __restrict__ W,
                      const float* __restrict__ b, float* __restrict__ q) {
    int g = blockIdx.x, o = threadIdx.x;
    float s = b[o];
    for (int k = 0; k < QD; ++k) s = fmaf(qe[g * QD + k], W[k * 64 + o], s);
    q[g * 64 + o] = fmaxf(s, 0.f);
}

__global__ void convert_x(const float* __restrict__ x, __hip_bfloat16* __restrict__ xb, int n4) {
    int i = blockIdx.x * blockDim.x + threadIdx.x;
    if (i >= n4) return;
    float4 v = ((const float4*)x)[i];
    union { ushort4 u; __hip_bfloat16 h[4]; } o;
    o.h[0] = __float2bfloat16(v.x); o.h[1] = __float2bfloat16(v.y);
    o.h[2] = __float2bfloat16(v.z); o.h[3] = __float2bfloat16(v.w);
    ((ushort4*)xb)[i] = o.u;
}

// WT[n][k] bf16, n in [0,5*O): slots 0..3 = W_r columns, slot 4 = root columns
__global__ void prep_w(const float* __restrict__ W, const float* __restrict__ root,
                       __hip_bfloat16* __restrict__ WT, int O) {
    int idx = blockIdx.x * blockDim.x + threadIdx.x;
    int total = 5 * O * 128;
    if (idx >= total) return;
    int n = idx >> 7, k = idx & 127;
    float v;
    if (n < 4 * O) { int r = n / O, o = n - r * O; v = W[((size_t)r * 128 + k) * O + o]; }
    else           { int o = n - 4 * O;            v = root[(size_t)k * O + o]; }
    WT[idx] = __float2bfloat16(v);
}

// ---------- CSR build ----------

__global__ void count_edges(const int* __restrict__ dst, const int* __restrict__ et,
                            int* __restrict__ cnt) {
    int e = blockIdx.x * blockDim.x + threadIdx.x;
    if (e < EE) atomicAdd(&cnt[dst[e] * 4 + et[e]], 1);
}

__global__ void inv_deg(const int* __restrict__ cnt, float* __restrict__ inv4,
                        int* __restrict__ deg) {
    int i = blockIdx.x * blockDim.x + threadIdx.x;
    if (i >= NN) return;
    int4 c = ((const int4*)cnt)[i];
    deg[i] = c.x + c.y + c.z + c.w;
    float4 iv;
    iv.x = 1.f / fmaxf((float)c.x, 1.f);
    iv.y = 1.f / fmaxf((float)c.y, 1.f);
    iv.z = 1.f / fmaxf((float)c.z, 1.f);
    iv.w = 1.f / fmaxf((float)c.w, 1.f);
    ((float4*)inv4)[i] = iv;
}

// hierarchical scan: pass1 block sums, pass2 scan of 49 sums, pass3 write offsets+cursor
__global__ void scan_bsum(const int* __restrict__ deg, int* __restrict__ bsum) {
    __shared__ int wt[4];
    int tid = threadIdx.x, blk = blockIdx.x;
    int i0 = blk * 1024 + tid * 4;
    int s = 0;
#pragma unroll
    for (int k = 0; k < 4; ++k) { int i = i0 + k; if (i < NN) s += deg[i]; }
    for (int off = 32; off; off >>= 1) s += __shfl_down(s, off, 64);
    if ((tid & 63) == 0) wt[tid >> 6] = s;
    __syncthreads();
    if (tid == 0) bsum[blk] = wt[0] + wt[1] + wt[2] + wt[3];
}

__global__ void scan_bscan(int* __restrict__ bsum, int* __restrict__ offsets) {
    int lane = threadIdx.x;
    int v = (lane < SCAN_BLK) ? bsum[lane] : 0;
    int sc = v;
#pragma unroll
    for (int off = 1; off < 64; off <<= 1) {
        int t = __shfl_up(sc, off, 64);
        if (lane >= off) sc += t;
    }
    if (lane < SCAN_BLK) bsum[lane] = sc - v;   // exclusive
    if (lane == 0) offsets[NN] = EE;
}

__global__ void scan_write(const int* __restrict__ deg, const int* __restrict__ bsum,
                           int* __restrict__ offsets, int* __restrict__ cursor) {
    __shared__ int wtot[4];
    int tid = threadIdx.x, lane = tid & 63, w = tid >> 6, blk = blockIdx.x;
    int i0 = blk * 1024 + tid * 4;
    int v[4];
#pragma unroll
    for (int k = 0; k < 4; ++k) { int i = i0 + k; v[k] = (i < NN) ? deg[i] : 0; }
    int tsum = v[0] + v[1] + v[2] + v[3];
    int sc = tsum;
#pragma unroll
    for (int off = 1; off < 64; off <<= 1) {
        int t = __shfl_up(sc, off, 64);
        if (lane >= off) sc += t;
    }
    if (lane == 63) wtot[w] = sc;
    __syncthreads();
    int wbase = 0;
    for (int ww = 0; ww < w; ++ww) wbase += wtot[ww];
    int texcl = bsum[blk] + wbase + sc - tsum;
#pragma unroll
    for (int k = 0; k < 4; ++k) {
        int i = i0 + k;
        if (i < NN) { offsets[i] = texcl; cursor[i] = texcl; }
        texcl += v[k];
    }
}

// csr entry: (src<<2)|rel  -> directly indexes hall_b[node][rel] layout
__global__ void scatter_edges(const int* __restrict__ src, const int* __restrict__ dst,
                              const int* __restrict__ et, int* __restrict__ cursor,
                              int* __restrict__ csr) {
    int e = blockIdx.x * blockDim.x + threadIdx.x;
    if (e >= EE) return;
    int p = atomicAdd(&cursor[dst[e]], 1);
    csr[p] = (src[e] << 2) | et[e];
}

// ---------- dense: hall_b[node][rel][O] bf16 (rel transforms), hroot[node][O] fp32 ----------
// Loop inversion vs R4: grid=(cg, rowgroup). Each wave holds ONE cg's 16
// b-fragments in registers (64 VGPRs) and sweeps 8 row tiles, so the 16KB
// W hot-set is read 8x less from L2 (500MB -> 62MB) and X rows are shared
// by consecutively-dispatched blocks (cg is the fast grid dim).

template <int O>
__global__ __launch_bounds__(256) void dense_mm(const __hip_bfloat16* __restrict__ X,
                                                const __hip_bfloat16* __restrict__ WT,
                                                __hip_bfloat16* __restrict__ hall_b,
                                                float* __restrict__ hroot) {
    __shared__ char tilebuf[4][4096];   // per-wave repack tile
    int wave = threadIdx.x >> 6;
    int lane = threadIdx.x & 63;
    int quad = lane >> 4, l15 = lane & 15;
    int cg = blockIdx.x;
    int slot = (O == 64) ? cg : (cg >> 1);
    int colbase = (O == 128 && (cg & 1)) ? 64 : 0;
    const __bf16* Xs = (const __bf16*)X;
    const __bf16* Ws = (const __bf16*)WT;

    // one cg's W fragments, held in registers for the whole row sweep
    bf16x8 b[4][4];
#pragma unroll
    for (int kk = 0; kk < 4; ++kk)
#pragma unroll
        for (int t = 0; t < 4; ++t)
            b[kk][t] = *(const bf16x8*)(Ws + (size_t)(cg * 64 + t * 16 + l15) * 128 + kk * 32 + quad * 8);

    int tile0 = blockIdx.y * 32 + wave * 8;
    for (int i = 0; i < 8; ++i) {
        int tile = tile0 + i;
        if (tile >= NN / 16) break;
        int m0 = tile * 16;

        bf16x8 a[4];
#pragma unroll
        for (int kk = 0; kk < 4; ++kk)
            a[kk] = *(const bf16x8*)(Xs + (size_t)(m0 + l15) * 128 + kk * 32 + quad * 8);

        f32x4 acc[4] = {f32x4{0,0,0,0}, f32x4{0,0,0,0}, f32x4{0,0,0,0}, f32x4{0,0,0,0}};
#pragma unroll
        for (int kk = 0; kk < 4; ++kk)
#pragma unroll
            for (int t = 0; t < 4; ++t)
                acc[t] = __builtin_amdgcn_mfma_f32_16x16x32_bf16(a[kk], b[kk][t], acc[t], 0, 0, 0);

        if (slot == 4) {
            // root fp32: repack 16x64 f32 tile -> 16B/lane coalesced stores
            float* tp = (float*)tilebuf[wave];
#pragma unroll
            for (int t = 0; t < 4; ++t)
#pragma unroll
                for (int reg = 0; reg < 4; ++reg)
                    tp[(quad * 4 + reg) * 64 + t * 16 + l15] = acc[t][reg];
#pragma unroll
            for (int p = 0; p < 4; ++p) {
                int c = p * 64 + lane;          // 16B chunk: row = c>>4, col0 = (c&15)*4
                int row = c >> 4, col0 = (c & 15) * 4;
                *(f32x4*)&hroot[(size_t)(m0 + row) * O + colbase + col0] =
                    ((const f32x4*)tp)[c];
            }
        } else {
            // bf16: repack 16x64 bf16 tile -> 16B/lane coalesced stores
            __hip_bfloat16* tp = (__hip_bfloat16*)tilebuf[wave];
#pragma unroll
            for (int t = 0; t < 4; ++t)
#pragma unroll
                for (int reg = 0; reg < 4; ++reg)
                    tp[(quad * 4 + reg) * 64 + t * 16 + l15] = __float2bfloat16(acc[t][reg]);
#pragma unroll
            for (int p = 0; p < 2; ++p) {
                int c = p * 64 + lane;          // 16B chunk: row = c>>3, col0 = (c&7)*8
                int row = c >> 3, col0 = (c & 7) * 8;
                *(uint4*)&hall_b[((size_t)(m0 + row) * 4 + slot) * O + colbase + col0] =
                    ((const uint4*)tp)[c];
            }
        }
    }
}

// ---------- aggregate ----------
// MODE 0: layer0 (O=64): relu, write bf16 [h | q[batch]] into xnext (128 cols)
// MODE 1: mid   (O=128): relu, write bf16 into xnext
// MODE 2: last  (O=64): no relu, write fp32 to out

template <int O, int MODE>
__global__ __launch_bounds__(256) void aggregate(const __hip_bfloat16* __restrict__ hall_b,
                                                 const float* __restrict__ hroot,
                                                 const int* __restrict__ offsets,
                                                 const int* __restrict__ csr,
                                                 const float* __restrict__ inv4,
                                                 const float* __restrict__ bias,
                                                 const float* __restrict__ q,
                                                 const int* __restrict__ batch,
                                                 __hip_bfloat16* __restrict__ xnext,
                                                 float* __restrict__ out) {
    int node = blockIdx.x * 4 + (threadIdx.x >> 6);
    int lane = threadIdx.x & 63;
    int e0 = offsets[node], e1 = offsets[node + 1];
    float4 iv = ((const float4*)inv4)[node];
    float acc0 = 0.f, acc1 = 0.f;
    const char* hb = (const char*)hall_b;
    for (int base = e0; base < e1; base += 64) {
        int e = base + lane;
        int packed = (e < e1) ? csr[e] : 0;
        int m = min(64, e1 - base);
        int j = 0;
        // 4x unrolled: 4 independent gather loads in flight
        for (; j + 4 <= m; j += 4) {
            int p0 = __builtin_amdgcn_readlane(packed, j);
            int p1 = __builtin_amdgcn_readlane(packed, j + 1);
            int p2 = __builtin_amdgcn_readlane(packed, j + 2);
            int p3 = __builtin_amdgcn_readlane(packed, j + 3);
            int r0 = p0 & 3, r1 = p1 & 3, r2 = p2 & 3, r3 = p3 & 3;
            float w0 = (r0 == 0) ? iv.x : (r0 == 1) ? iv.y : (r0 == 2) ? iv.z : iv.w;
            float w1 = (r1 == 0) ? iv.x : (r1 == 1) ? iv.y : (r1 == 2) ? iv.z : iv.w;
            float w2 = (r2 == 0) ? iv.x : (r2 == 1) ? iv.y : (r2 == 2) ? iv.z : iv.w;
            float w3 = (r3 == 0) ? iv.x : (r3 == 1) ? iv.y : (r3 == 2) ? iv.z : iv.w;
            if (O == 64) {
                unsigned u0 = *(const unsigned short*)(hb + (size_t)p0 * 128 + lane * 2);
                unsigned u1 = *(const unsigned short*)(hb + (size_t)p1 * 128 + lane * 2);
                unsigned u2 = *(const unsigned short*)(hb + (size_t)p2 * 128 + lane * 2);
                unsigned u3 = *(const unsigned short*)(hb + (size_t)p3 * 128 + lane * 2);
                acc0 = fmaf(w0, bflo(u0), acc0);
                acc0 = fmaf(w1, bflo(u1), acc0);
                acc0 = fmaf(w2, bflo(u2), acc0);
                acc0 = fmaf(w3, bflo(u3), acc0);
            } else {
                unsigned u0 = *(const unsigned*)(hb + (size_t)p0 * 256 + lane * 4);
                unsigned u1 = *(const unsigned*)(hb + (size_t)p1 * 256 + lane * 4);
                unsigned u2 = *(const unsigned*)(hb + (size_t)p2 * 256 + lane * 4);
                unsigned u3 = *(const unsigned*)(hb + (size_t)p3 * 256 + lane * 4);
                acc0 = fmaf(w0, bflo(u0), acc0);  acc1 = fmaf(w0, bfhi(u0), acc1);
                acc0 = fmaf(w1, bflo(u1), acc0);  acc1 = fmaf(w1, bfhi(u1), acc1);
                acc0 = fmaf(w2, bflo(u2), acc0);  acc1 = fmaf(w2, bfhi(u2), acc1);
                acc0 = fmaf(w3, bflo(u3), acc0);  acc1 = fmaf(w3, bfhi(u3), acc1);
            }
        }
        for (; j < m; ++j) {
            int p = __builtin_amdgcn_readlane(packed, j);
            int r = p & 3;
            float wgt = (r == 0) ? iv.x : (r == 1) ? iv.y : (r == 2) ? iv.z : iv.w;
            if (O == 64) {
                unsigned u = *(const unsigned short*)(hb + (size_t)p * 128 + lane * 2);
                acc0 = fmaf(wgt, bflo(u), acc0);
            } else {
                unsigned u = *(const unsigned*)(hb + (size_t)p * 256 + lane * 4);
                acc0 = fmaf(wgt, bflo(u), acc0);
                acc1 = fmaf(wgt, bfhi(u), acc1);
            }
        }
    }
    if (MODE == 0) {
        float v0 = hroot[(size_t)node * 64 + lane] + bias[lane] + acc0;
        xnext[(size_t)node * 128 + lane] = __float2bfloat16(fmaxf(v0, 0.f));
        float qv = q[batch[node] * 64 + lane];
        xnext[(size_t)node * 128 + 64 + lane] = __float2bfloat16(qv);
    } else if (MODE == 1) {
        float2 rr = *(const float2*)(hroot + (size_t)node * 128 + 2 * lane);
        float2 bb = *(const float2*)(bias + 2 * lane);
        float v0 = fmaxf(rr.x + bb.x + acc0, 0.f);
        float v1 = fmaxf(rr.y + bb.y + acc1, 0.f);
        __hip_bfloat16 h0 = __float2bfloat16(v0), h1 = __float2bfloat16(v1);
        ushort2 pk;
        pk.x = *(unsigned short*)&h0; pk.y = *(unsigned short*)&h1;
        ((ushort2*)xnext)[(size_t)node * 64 + lane] = pk;
    } else {
        out[(size_t)node * 64 + lane] = hroot[(size_t)node * 64 + lane] + bias[lane] + acc0;
    }
}

// ---------- launch ----------

static inline size_t rup(size_t x) { return (x + 255) & ~(size_t)255; }

extern "C" void kernel_launch(void* const* d_in, const int* in_sizes, int n_in,
                              void* d_out, int out_size, void* d_ws, size_t ws_size,
                              hipStream_t stream) {
    const float* x      = (const float*)d_in[0];
    const int*   esrc   = (const int*)d_in[1];
    const int*   edst   = esrc + EE;
    const int*   eattr  = (const int*)d_in[2];
    const int*   batch  = (const int*)d_in[3];
    const float* qe     = (const float*)d_in[4];
    const float* qn_W   = (const float*)d_in[5];
    const float* qn_b   = (const float*)d_in[6];
    const float* W0 = (const float*)d_in[7],  *root0 = (const float*)d_in[8],  *b0 = (const float*)d_in[9];
    const float* W1 = (const float*)d_in[10], *root1 = (const float*)d_in[11], *b1 = (const float*)d_in[12];
    const float* W2 = (const float*)d_in[13], *root2 = (const float*)d_in[14], *b2 = (const float*)d_in[15];
    const float* W3 = (const float*)d_in[16], *root3 = (const float*)d_in[17], *b3 = (const float*)d_in[18];
    float* out = (float*)d_out;

    char* w = (char*)d_ws;
    float* q       = (float*)w;  w += rup(GG * 64 * 4);
    int*   cnt     = (int*)w;    w += rup((size_t)NN * 4 * 4);
    float* inv4    = (float*)w;  w += rup((size_t)NN * 4 * 4);
    int*   deg     = (int*)w;    w += rup((size_t)NN * 4);
    int*   offsets = (int*)w;    w += rup(((size_t)NN + 1) * 4);
    int*   cursor  = (int*)w;    w += rup((size_t)NN * 4);
    int*   bsum    = (int*)w;    w += rup((size_t)SCAN_BLK * 4);
    int*   csr     = (int*)w;    w += rup((size_t)EE * 4);
    __hip_bfloat16* WT0 = (__hip_bfloat16*)w; w += rup((size_t)5 * 64 * 128 * 2);
    __hip_bfloat16* WT1 = (__hip_bfloat16*)w; w += rup((size_t)5 * 128 * 128 * 2);
    __hip_bfloat16* WT2 = (__hip_bfloat16*)w; w += rup((size_t)5 * 128 * 128 * 2);
    __hip_bfloat16* WT3 = (__hip_bfloat16*)w; w += rup((size_t)5 * 64 * 128 * 2);
    __hip_bfloat16* xb0 = (__hip_bfloat16*)w; w += rup((size_t)NN * 128 * 2);
    __hip_bfloat16* xb1 = (__hip_bfloat16*)w; w += rup((size_t)NN * 128 * 2);
    __hip_bfloat16* hall_b = (__hip_bfloat16*)w; w += rup((size_t)NN * 4 * 128 * 2);
    float* hroot   = (float*)w;  w += rup((size_t)NN * 128 * 4);

    hipMemsetAsync(cnt, 0, (size_t)NN * 4 * 4, stream);

    // question projection + input conversion + weight prep
    qkern<<<GG, 64, 0, stream>>>(qe, qn_W, qn_b, q);
    convert_x<<<(NN * 128 / 4 + 255) / 256, 256, 0, stream>>>(x, xb0, NN * 128 / 4);
    prep_w<<<(5 * 64 * 128 + 255) / 256, 256, 0, stream>>>(W0, root0, WT0, 64);
    prep_w<<<(5 * 128 * 128 + 255) / 256, 256, 0, stream>>>(W1, root1, WT1, 128);
    prep_w<<<(5 * 128 * 128 + 255) / 256, 256, 0, stream>>>(W2, root2, WT2, 128);
    prep_w<<<(5 * 64 * 128 + 255) / 256, 256, 0, stream>>>(W3, root3, WT3, 64);

    // CSR build
    int eb = (EE + 255) / 256;
    count_edges<<<eb, 256, 0, stream>>>(edst, eattr, cnt);
    inv_deg<<<(NN + 255) / 256, 256, 0, stream>>>(cnt, inv4, deg);
    scan_bsum<<<SCAN_BLK, 256, 0, stream>>>(deg, bsum);
    scan_bscan<<<1, 64, 0, stream>>>(bsum, offsets);
    scan_write<<<SCAN_BLK, 256, 0, stream>>>(deg, bsum, offsets, cursor);
    scatter_edges<<<eb, 256, 0, stream>>>(esrc, edst, eattr, cursor, csr);

    int rowgrp = (NN / 16 + 31) / 32;  // 98 groups of 32 row tiles
    int aggblk = NN / 4;               // 12500

    // layer 0: x(bf16) -> hall(O=64) -> combined (xb1)
    dense_mm<64><<<dim3(5, rowgrp), 256, 0, stream>>>(xb0, WT0, hall_b, hroot);
    aggregate<64, 0><<<aggblk, 256, 0, stream>>>(hall_b, hroot, offsets, csr, inv4, b0, q, batch, xb1, nullptr);

    // layer 1: combined -> hall(O=128) -> xb0
    dense_mm<128><<<dim3(10, rowgrp), 256, 0, stream>>>(xb1, WT1, hall_b, hroot);
    aggregate<128, 1><<<aggblk, 256, 0, stream>>>(hall_b, hroot, offsets, csr, inv4, b1, nullptr, nullptr, xb0, nullptr);

    // layer 2: -> xb1
    dense_mm<128><<<dim3(10, rowgrp), 256, 0, stream>>>(xb0, WT2, hall_b, hroot);
    aggregate<128, 1><<<aggblk, 256, 0, stream>>>(hall_b, hroot, offsets, csr, inv4, b2, nullptr, nullptr, xb1, nullptr);

    // layer 3: -> d_out (fp32, no relu)
    dense_mm<64><<<dim3(5, rowgrp), 256, 0, stream>>>(xb1, WT3, hall_b, hroot);
    aggregate<64, 2><<<aggblk, 256, 0, stream>>>(hall_b, hroot, offsets, csr, inv4, b3, nullptr, nullptr, nullptr, out);
}

// Round 7
// 435.321 us; speedup vs baseline: 1.6396x; 1.1228x over previous
//
#include <hip/hip_runtime.h>
#include <hip/hip_bf16.h>

#define NN 50000
#define EE 800000
#define GG 16
#define QD 768
#define NBUCK 196      // ceil(50000/256) dst-buckets of 256 nodes
#define EPB 4000       // edges per block in bin_edges (200 blocks)

typedef __bf16 bf16x8 __attribute__((ext_vector_type(8)));
typedef float f32x4 __attribute__((ext_vector_type(4)));

static __device__ __forceinline__ float bflo(unsigned u) {
    union { unsigned v; float f; } c; c.v = u << 16; return c.f;
}
static __device__ __forceinline__ float bfhi(unsigned u) {
    union { unsigned v; float f; } c; c.v = u & 0xffff0000u; return c.f;
}

// ---------- small prep kernels ----------

__global__ void qkern(const float* __restrict__ qe, const float* __restrict__ W,
                      const float* __restrict__ b, float* __restrict__ q) {
    int g = blockIdx.x, o = threadIdx.x;
    float s = b[o];
    for (int k = 0; k < QD; ++k) s = fmaf(qe[g * QD + k], W[k * 64 + o], s);
    q[g * 64 + o] = fmaxf(s, 0.f);
}

__global__ void convert_x(const float* __restrict__ x, __hip_bfloat16* __restrict__ xb, int n4) {
    int i = blockIdx.x * blockDim.x + threadIdx.x;
    if (i >= n4) return;
    float4 v = ((const float4*)x)[i];
    union { ushort4 u; __hip_bfloat16 h[4]; } o;
    o.h[0] = __float2bfloat16(v.x); o.h[1] = __float2bfloat16(v.y);
    o.h[2] = __float2bfloat16(v.z); o.h[3] = __float2bfloat16(v.w);
    ((ushort4*)xb)[i] = o.u;
}

// WT[n][k] bf16, n in [0,5*O): slots 0..3 = W_r columns, slot 4 = root columns
__global__ void prep_w(const float* __restrict__ W, const float* __restrict__ root,
                       __hip_bfloat16* __restrict__ WT, int O) {
    int idx = blockIdx.x * blockDim.x + threadIdx.x;
    int total = 5 * O * 128;
    if (idx >= total) return;
    int n = idx >> 7, k = idx & 127;
    float v;
    if (n < 4 * O) { int r = n / O, o = n - r * O; v = W[((size_t)r * 128 + k) * O + o]; }
    else           { int o = n - 4 * O;            v = root[(size_t)k * O + o]; }
    WT[idx] = __float2bfloat16(v);
}

// ---------- CSR build: two-level bucket sort ----------
// bucket b = dst >> 8 (256 nodes / bucket). binned entry: (src<<10)|(rel<<8)|(dst&255)

__global__ void bucket_hist(const int* __restrict__ dst, int* __restrict__ bcnt) {
    __shared__ int h[NBUCK];
    int tid = threadIdx.x;
    for (int i = tid; i < NBUCK; i += 256) h[i] = 0;
    __syncthreads();
    for (int e = blockIdx.x * 256 + tid; e < EE; e += gridDim.x * 256)
        atomicAdd(&h[dst[e] >> 8], 1);
    __syncthreads();
    for (int i = tid; i < NBUCK; i += 256) if (h[i]) atomicAdd(&bcnt[i], h[i]);
}

__global__ void bucket_scan(const int* __restrict__ bcnt, int* __restrict__ bbase,
                            int* __restrict__ bcur) {
    __shared__ int wt[4];
    int tid = threadIdx.x, lane = tid & 63, w = tid >> 6;
    int v = (tid < NBUCK) ? bcnt[tid] : 0;
    int sc = v;
#pragma unroll
    for (int off = 1; off < 64; off <<= 1) {
        int t = __shfl_up(sc, off, 64);
        if (lane >= off) sc += t;
    }
    if (lane == 63) wt[w] = sc;
    __syncthreads();
    int wbase = 0;
    for (int ww = 0; ww < w; ++ww) wbase += wt[ww];
    int excl = wbase + sc - v;
    if (tid <= NBUCK) bbase[tid] = excl;   // tid==NBUCK gets total == EE
    if (tid < NBUCK) bcur[tid] = excl;
}

// LDS-ranked binning: each block reserves contiguous runs per bucket -> dense writes
__global__ __launch_bounds__(256) void bin_edges(const int* __restrict__ src,
                                                 const int* __restrict__ dst,
                                                 const int* __restrict__ et,
                                                 int* __restrict__ bcur,
                                                 unsigned* __restrict__ binned) {
    __shared__ int lcnt[NBUCK];
    __shared__ int lbase[NBUCK];
    int tid = threadIdx.x;
    int e0 = blockIdx.x * EPB, e1 = min(e0 + EPB, EE);
    for (int base = e0; base < e1; base += 2048) {
        for (int i = tid; i < NBUCK; i += 256) lcnt[i] = 0;
        __syncthreads();
        unsigned ent[8]; int bk[8], rk[8];
#pragma unroll
        for (int k = 0; k < 8; ++k) {
            int e = base + k * 256 + tid;
            if (e < e1) {
                int d = dst[e];
                bk[k] = d >> 8;
                ent[k] = ((unsigned)src[e] << 10) | ((unsigned)et[e] << 8) | (unsigned)(d & 255);
                rk[k] = atomicAdd(&lcnt[bk[k]], 1);
            } else bk[k] = -1;
        }
        __syncthreads();
        for (int i = tid; i < NBUCK; i += 256)
            lbase[i] = lcnt[i] ? atomicAdd(&bcur[i], lcnt[i]) : 0;
        __syncthreads();
#pragma unroll
        for (int k = 0; k < 8; ++k)
            if (bk[k] >= 0) binned[lbase[bk[k]] + rk[k]] = ent[k];
        __syncthreads();
    }
}

// per-bucket fine CSR: count -> scan -> scatter, all in LDS; emits csr/offsets/inv4
__global__ __launch_bounds__(256) void csr_fine(const int* __restrict__ bbase,
                                                const unsigned* __restrict__ binned,
                                                int* __restrict__ csr,
                                                int* __restrict__ offsets,
                                                float* __restrict__ inv4) {
    __shared__ int cnt[1024];   // 256 nodes x 4 rels
    __shared__ int wt[4];
    int b = blockIdx.x, tid = threadIdx.x, lane = tid & 63, w = tid >> 6;
    int seg0 = bbase[b], seg1 = bbase[b + 1];
    for (int i = tid; i < 1024; i += 256) cnt[i] = 0;
    __syncthreads();
    for (int e = seg0 + tid; e < seg1; e += 256) {
        unsigned u = binned[e];
        atomicAdd(&cnt[(u & 255) * 4 + ((u >> 8) & 3)], 1);
    }
    __syncthreads();
    // thread t owns node t's 4 counters; block exclusive scan over 1024
    int c0 = cnt[tid * 4], c1 = cnt[tid * 4 + 1], c2 = cnt[tid * 4 + 2], c3 = cnt[tid * 4 + 3];
    int s = c0 + c1 + c2 + c3;
    int sc = s;
#pragma unroll
    for (int off = 1; off < 64; off <<= 1) {
        int t = __shfl_up(sc, off, 64);
        if (lane >= off) sc += t;
    }
    if (lane == 63) wt[w] = sc;
    __syncthreads();
    int wbase = 0;
    for (int ww = 0; ww < w; ++ww) wbase += wt[ww];
    int excl = wbase + sc - s;
    // own slots only -> no race
    cnt[tid * 4]     = excl;
    cnt[tid * 4 + 1] = excl + c0;
    cnt[tid * 4 + 2] = excl + c0 + c1;
    cnt[tid * 4 + 3] = excl + c0 + c1 + c2;
    int node = b * 256 + tid;
    if (node < NN) {
        offsets[node] = seg0 + excl;
        float4 iv;
        iv.x = 1.f / fmaxf((float)c0, 1.f);
        iv.y = 1.f / fmaxf((float)c1, 1.f);
        iv.z = 1.f / fmaxf((float)c2, 1.f);
        iv.w = 1.f / fmaxf((float)c3, 1.f);
        ((float4*)inv4)[node] = iv;
    }
    if (b == NBUCK - 1 && tid == 0) offsets[NN] = EE;
    __syncthreads();
    for (int e = seg0 + tid; e < seg1; e += 256) {
        unsigned u = binned[e];
        int r = atomicAdd(&cnt[(u & 255) * 4 + ((u >> 8) & 3)], 1);
        csr[seg0 + r] = (int)(((u >> 10) << 2) | ((u >> 8) & 3));   // (src<<2)|rel
    }
}

// ---------- dense: hall_b[node][rel][O] bf16 (rel transforms), hroot[node][O] fp32 ----------
// grid=(cg, rowgroup); each wave holds one cg's 16 W-fragments in registers and
// sweeps 8 row tiles (W L2 traffic 8x lower; X shared via fast cg grid dim).

template <int O>
__global__ __launch_bounds__(256) void dense_mm(const __hip_bfloat16* __restrict__ X,
                                                const __hip_bfloat16* __restrict__ WT,
                                                __hip_bfloat16* __restrict__ hall_b,
                                                float* __restrict__ hroot) {
    __shared__ char tilebuf[4][4096];   // per-wave repack tile
    int wave = threadIdx.x >> 6;
    int lane = threadIdx.x & 63;
    int quad = lane >> 4, l15 = lane & 15;
    int cg = blockIdx.x;
    int slot = (O == 64) ? cg : (cg >> 1);
    int colbase = (O == 128 && (cg & 1)) ? 64 : 0;
    const __bf16* Xs = (const __bf16*)X;
    const __bf16* Ws = (const __bf16*)WT;

    bf16x8 b[4][4];
#pragma unroll
    for (int kk = 0; kk < 4; ++kk)
#pragma unroll
        for (int t = 0; t < 4; ++t)
            b[kk][t] = *(const bf16x8*)(Ws + (size_t)(cg * 64 + t * 16 + l15) * 128 + kk * 32 + quad * 8);

    int tile0 = blockIdx.y * 32 + wave * 8;
    for (int i = 0; i < 8; ++i) {
        int tile = tile0 + i;
        if (tile >= NN / 16) break;
        int m0 = tile * 16;

        bf16x8 a[4];
#pragma unroll
        for (int kk = 0; kk < 4; ++kk)
            a[kk] = *(const bf16x8*)(Xs + (size_t)(m0 + l15) * 128 + kk * 32 + quad * 8);

        f32x4 acc[4] = {f32x4{0,0,0,0}, f32x4{0,0,0,0}, f32x4{0,0,0,0}, f32x4{0,0,0,0}};
#pragma unroll
        for (int kk = 0; kk < 4; ++kk)
#pragma unroll
            for (int t = 0; t < 4; ++t)
                acc[t] = __builtin_amdgcn_mfma_f32_16x16x32_bf16(a[kk], b[kk][t], acc[t], 0, 0, 0);

        if (slot == 4) {
            float* tp = (float*)tilebuf[wave];
#pragma unroll
            for (int t = 0; t < 4; ++t)
#pragma unroll
                for (int reg = 0; reg < 4; ++reg)
                    tp[(quad * 4 + reg) * 64 + t * 16 + l15] = acc[t][reg];
#pragma unroll
            for (int p = 0; p < 4; ++p) {
                int c = p * 64 + lane;
                int row = c >> 4, col0 = (c & 15) * 4;
                *(f32x4*)&hroot[(size_t)(m0 + row) * O + colbase + col0] =
                    ((const f32x4*)tp)[c];
            }
        } else {
            __hip_bfloat16* tp = (__hip_bfloat16*)tilebuf[wave];
#pragma unroll
            for (int t = 0; t < 4; ++t)
#pragma unroll
                for (int reg = 0; reg < 4; ++reg)
                    tp[(quad * 4 + reg) * 64 + t * 16 + l15] = __float2bfloat16(acc[t][reg]);
#pragma unroll
            for (int p = 0; p < 2; ++p) {
                int c = p * 64 + lane;
                int row = c >> 3, col0 = (c & 7) * 8;
                *(uint4*)&hall_b[((size_t)(m0 + row) * 4 + slot) * O + colbase + col0] =
                    ((const uint4*)tp)[c];
            }
        }
    }
}

// ---------- aggregate ----------
// MODE 0: layer0 (O=64): relu, write bf16 [h | q[batch]] into xnext (128 cols)
// MODE 1: mid   (O=128): relu, write bf16 into xnext
// MODE 2: last  (O=64): no relu, write fp32 to out

template <int O, int MODE>
__global__ __launch_bounds__(256) void aggregate(const __hip_bfloat16* __restrict__ hall_b,
                                                 const float* __restrict__ hroot,
                                                 const int* __restrict__ offsets,
                                                 const int* __restrict__ csr,
                                                 const float* __restrict__ inv4,
                                                 const float* __restrict__ bias,
                                                 const float* __restrict__ q,
                                                 const int* __restrict__ batch,
                                                 __hip_bfloat16* __restrict__ xnext,
                                                 float* __restrict__ out) {
    int node = blockIdx.x * 4 + (threadIdx.x >> 6);
    int lane = threadIdx.x & 63;
    int e0 = offsets[node], e1 = offsets[node + 1];
    float4 iv = ((const float4*)inv4)[node];
    float acc0 = 0.f, acc1 = 0.f;
    const char* hb = (const char*)hall_b;
    for (int base = e0; base < e1; base += 64) {
        int e = base + lane;
        int packed = (e < e1) ? csr[e] : 0;
        int m = min(64, e1 - base);
        int j = 0;
        for (; j + 4 <= m; j += 4) {
            int p0 = __builtin_amdgcn_readlane(packed, j);
            int p1 = __builtin_amdgcn_readlane(packed, j + 1);
            int p2 = __builtin_amdgcn_readlane(packed, j + 2);
            int p3 = __builtin_amdgcn_readlane(packed, j + 3);
            int r0 = p0 & 3, r1 = p1 & 3, r2 = p2 & 3, r3 = p3 & 3;
            float w0 = (r0 == 0) ? iv.x : (r0 == 1) ? iv.y : (r0 == 2) ? iv.z : iv.w;
            float w1 = (r1 == 0) ? iv.x : (r1 == 1) ? iv.y : (r1 == 2) ? iv.z : iv.w;
            float w2 = (r2 == 0) ? iv.x : (r2 == 1) ? iv.y : (r2 == 2) ? iv.z : iv.w;
            float w3 = (r3 == 0) ? iv.x : (r3 == 1) ? iv.y : (r3 == 2) ? iv.z : iv.w;
            if (O == 64) {
                unsigned u0 = *(const unsigned short*)(hb + (size_t)p0 * 128 + lane * 2);
                unsigned u1 = *(const unsigned short*)(hb + (size_t)p1 * 128 + lane * 2);
                unsigned u2 = *(const unsigned short*)(hb + (size_t)p2 * 128 + lane * 2);
                unsigned u3 = *(const unsigned short*)(hb + (size_t)p3 * 128 + lane * 2);
                acc0 = fmaf(w0, bflo(u0), acc0);
                acc0 = fmaf(w1, bflo(u1), acc0);
                acc0 = fmaf(w2, bflo(u2), acc0);
                acc0 = fmaf(w3, bflo(u3), acc0);
            } else {
                unsigned u0 = *(const unsigned*)(hb + (size_t)p0 * 256 + lane * 4);
                unsigned u1 = *(const unsigned*)(hb + (size_t)p1 * 256 + lane * 4);
                unsigned u2 = *(const unsigned*)(hb + (size_t)p2 * 256 + lane * 4);
                unsigned u3 = *(const unsigned*)(hb + (size_t)p3 * 256 + lane * 4);
                acc0 = fmaf(w0, bflo(u0), acc0);  acc1 = fmaf(w0, bfhi(u0), acc1);
                acc0 = fmaf(w1, bflo(u1), acc0);  acc1 = fmaf(w1, bfhi(u1), acc1);
                acc0 = fmaf(w2, bflo(u2), acc0);  acc1 = fmaf(w2, bfhi(u2), acc1);
                acc0 = fmaf(w3, bflo(u3), acc0);  acc1 = fmaf(w3, bfhi(u3), acc1);
            }
        }
        for (; j < m; ++j) {
            int p = __builtin_amdgcn_readlane(packed, j);
            int r = p & 3;
            float wgt = (r == 0) ? iv.x : (r == 1) ? iv.y : (r == 2) ? iv.z : iv.w;
            if (O == 64) {
                unsigned u = *(const unsigned short*)(hb + (size_t)p * 128 + lane * 2);
                acc0 = fmaf(wgt, bflo(u), acc0);
            } else {
                unsigned u = *(const unsigned*)(hb + (size_t)p * 256 + lane * 4);
                acc0 = fmaf(wgt, bflo(u), acc0);
                acc1 = fmaf(wgt, bfhi(u), acc1);
            }
        }
    }
    if (MODE == 0) {
        float v0 = hroot[(size_t)node * 64 + lane] + bias[lane] + acc0;
        xnext[(size_t)node * 128 + lane] = __float2bfloat16(fmaxf(v0, 0.f));
        float qv = q[batch[node] * 64 + lane];
        xnext[(size_t)node * 128 + 64 + lane] = __float2bfloat16(qv);
    } else if (MODE == 1) {
        float2 rr = *(const float2*)(hroot + (size_t)node * 128 + 2 * lane);
        float2 bb = *(const float2*)(bias + 2 * lane);
        float v0 = fmaxf(rr.x + bb.x + acc0, 0.f);
        float v1 = fmaxf(rr.y + bb.y + acc1, 0.f);
        __hip_bfloat16 h0 = __float2bfloat16(v0), h1 = __float2bfloat16(v1);
        ushort2 pk;
        pk.x = *(unsigned short*)&h0; pk.y = *(unsigned short*)&h1;
        ((ushort2*)xnext)[(size_t)node * 64 + lane] = pk;
    } else {
        out[(size_t)node * 64 + lane] = hroot[(size_t)node * 64 + lane] + bias[lane] + acc0;
    }
}

// ---------- launch ----------

static inline size_t rup(size_t x) { return (x + 255) & ~(size_t)255; }

extern "C" void kernel_launch(void* const* d_in, const int* in_sizes, int n_in,
                              void* d_out, int out_size, void* d_ws, size_t ws_size,
                              hipStream_t stream) {
    const float* x      = (const float*)d_in[0];
    const int*   esrc   = (const int*)d_in[1];
    const int*   edst   = esrc + EE;
    const int*   eattr  = (const int*)d_in[2];
    const int*   batch  = (const int*)d_in[3];
    const float* qe     = (const float*)d_in[4];
    const float* qn_W   = (const float*)d_in[5];
    const float* qn_b   = (const float*)d_in[6];
    const float* W0 = (const float*)d_in[7],  *root0 = (const float*)d_in[8],  *b0 = (const float*)d_in[9];
    const float* W1 = (const float*)d_in[10], *root1 = (const float*)d_in[11], *b1 = (const float*)d_in[12];
    const float* W2 = (const float*)d_in[13], *root2 = (const float*)d_in[14], *b2 = (const float*)d_in[15];
    const float* W3 = (const float*)d_in[16], *root3 = (const float*)d_in[17], *b3 = (const float*)d_in[18];
    float* out = (float*)d_out;

    char* w = (char*)d_ws;
    float* q       = (float*)w;  w += rup(GG * 64 * 4);
    float* inv4    = (float*)w;  w += rup((size_t)NN * 4 * 4);
    int*   offsets = (int*)w;    w += rup(((size_t)NN + 1) * 4);
    int*   bcnt    = (int*)w;    w += rup((size_t)NBUCK * 4);
    int*   bbase   = (int*)w;    w += rup(((size_t)NBUCK + 1) * 4);
    int*   bcur    = (int*)w;    w += rup((size_t)NBUCK * 4);
    unsigned* binned = (unsigned*)w; w += rup((size_t)EE * 4);
    int*   csr     = (int*)w;    w += rup((size_t)EE * 4);
    __hip_bfloat16* WT0 = (__hip_bfloat16*)w; w += rup((size_t)5 * 64 * 128 * 2);
    __hip_bfloat16* WT1 = (__hip_bfloat16*)w; w += rup((size_t)5 * 128 * 128 * 2);
    __hip_bfloat16* WT2 = (__hip_bfloat16*)w; w += rup((size_t)5 * 128 * 128 * 2);
    __hip_bfloat16* WT3 = (__hip_bfloat16*)w; w += rup((size_t)5 * 64 * 128 * 2);
    __hip_bfloat16* xb0 = (__hip_bfloat16*)w; w += rup((size_t)NN * 128 * 2);
    __hip_bfloat16* xb1 = (__hip_bfloat16*)w; w += rup((size_t)NN * 128 * 2);
    __hip_bfloat16* hall_b = (__hip_bfloat16*)w; w += rup((size_t)NN * 4 * 128 * 2);
    float* hroot   = (float*)w;  w += rup((size_t)NN * 128 * 4);

    hipMemsetAsync(bcnt, 0, (size_t)NBUCK * 4, stream);

    // question projection + input conversion + weight prep
    qkern<<<GG, 64, 0, stream>>>(qe, qn_W, qn_b, q);
    convert_x<<<(NN * 128 / 4 + 255) / 256, 256, 0, stream>>>(x, xb0, NN * 128 / 4);
    prep_w<<<(5 * 64 * 128 + 255) / 256, 256, 0, stream>>>(W0, root0, WT0, 64);
    prep_w<<<(5 * 128 * 128 + 255) / 256, 256, 0, stream>>>(W1, root1, WT1, 128);
    prep_w<<<(5 * 128 * 128 + 255) / 256, 256, 0, stream>>>(W2, root2, WT2, 128);
    prep_w<<<(5 * 64 * 128 + 255) / 256, 256, 0, stream>>>(W3, root3, WT3, 64);

    // CSR build: bucket sort
    bucket_hist<<<256, 256, 0, stream>>>(edst, bcnt);
    bucket_scan<<<1, 256, 0, stream>>>(bcnt, bbase, bcur);
    bin_edges<<<(EE + EPB - 1) / EPB, 256, 0, stream>>>(esrc, edst, eattr, bcur, binned);
    csr_fine<<<NBUCK, 256, 0, stream>>>(bbase, binned, csr, offsets, inv4);

    int rowgrp = (NN / 16 + 31) / 32;  // 98 groups of 32 row tiles
    int aggblk = NN / 4;               // 12500

    // layer 0: x(bf16) -> hall(O=64) -> combined (xb1)
    dense_mm<64><<<dim3(5, rowgrp), 256, 0, stream>>>(xb0, WT0, hall_b, hroot);
    aggregate<64, 0><<<aggblk, 256, 0, stream>>>(hall_b, hroot, offsets, csr, inv4, b0, q, batch, xb1, nullptr);

    // layer 1: combined -> hall(O=128) -> xb0
    dense_mm<128><<<dim3(10, rowgrp), 256, 0, stream>>>(xb1, WT1, hall_b, hroot);
    aggregate<128, 1><<<aggblk, 256, 0, stream>>>(hall_b, hroot, offsets, csr, inv4, b1, nullptr, nullptr, xb0, nullptr);

    // layer 2: -> xb1
    dense_mm<128><<<dim3(10, rowgrp), 256, 0, stream>>>(xb0, WT2, hall_b, hroot);
    aggregate<128, 1><<<aggblk, 256, 0, stream>>>(hall_b, hroot, offsets, csr, inv4, b2, nullptr, nullptr, xb1, nullptr);

    // layer 3: -> d_out (fp32, no relu)
    dense_mm<64><<<dim3(5, rowgrp), 256, 0, stream>>>(xb1, WT3, hall_b, hroot);
    aggregate<64, 2><<<aggblk, 256, 0, stream>>>(hall_b, hroot, offsets, csr, inv4, b3, nullptr, nullptr, nullptr, out);
}